// Round 6
// baseline (1338.039 us; speedup 1.0000x reference)
//
#include <hip/hip_runtime.h>
#include <hip/hip_bf16.h>
#include <math.h>

#define S 1024
#define B 4
#define Dm 768
#define NH 12
#define DH 64
#define NL 4
#define DI 3072
#define QS 2304   // row stride of fused qkv activation buffer
#define MU_CHUNK 8   // S-dim split for memupd (partials fit exactly in out1 slot)
#define NROW (S * B * NH)   // 49152 attention rows

typedef __hip_bfloat16 bf16;
typedef short bf16x8 __attribute__((ext_vector_type(8)));
typedef float f32x4 __attribute__((ext_vector_type(4)));

__device__ __forceinline__ float b2f(bf16 x) { return __bfloat162float(x); }
__device__ __forceinline__ bf16 f2b(float x) { return __float2bfloat16(x); }

__device__ __forceinline__ float ldv(const float* p, size_t i) { return p[i]; }
__device__ __forceinline__ float ldv(const bf16* p, size_t i) { return b2f(p[i]); }

__device__ __forceinline__ float wave_sum(float x) {
  #pragma unroll
  for (int off = 32; off > 0; off >>= 1) x += __shfl_xor(x, off, 64);
  return x;
}

// async 16B global -> LDS DMA. LDS dest = wave-uniform base + lane*16.
typedef const __attribute__((address_space(1))) unsigned int guint;
typedef __attribute__((address_space(3))) unsigned int luint;
__device__ __forceinline__ void async_cp16(const void* g, void* l) {
  __builtin_amdgcn_global_load_lds((guint*)g, (luint*)l, 16, 0, 0);
}

// h[s,b,d] = word_emb[inp[s,b], d] * sqrt(D) + pos_emb(s, d); fp32 + bf16 copies
__global__ void embed_kernel(const int* __restrict__ inp, const float* __restrict__ wemb,
                             float* __restrict__ h, bf16* __restrict__ hb) {
  int idx = blockIdx.x * blockDim.x + threadIdx.x;
  if (idx >= S * B * Dm) return;
  int d = idx % Dm;
  int sb = idx / Dm;
  int b = sb % B;
  int s = sb / B;
  int tok = inp[s * B + b];
  float e = wemb[(size_t)tok * Dm + d] * 27.712812921102035f; // sqrt(768)
  float ps = (float)(S - 1 - s);
  float pe;
  if (d < Dm / 2) {
    float invf = expf(-(2.0f * (float)d / (float)Dm) * 9.210340371976184f); // ln(10000)
    pe = sinf(ps * invf);
  } else {
    int j = d - Dm / 2;
    float invf = expf(-(2.0f * (float)j / (float)Dm) * 9.210340371976184f);
    pe = cosf(ps * invf);
  }
  float val = e + pe;
  h[idx] = val;
  hb[idx] = f2b(val);
}

// pack one layer's weights to bf16 into wb:
//   [qkv 2304x768 | wo 768x768 | w1 3072x768 | w2 768x3072]  (all B^T, K contiguous)
#define SEG_QKV 1769472
#define SEG_WO  2359296
#define SEG_W1  4718592
#define SEG_END 7077888
__global__ void convw_kernel(const float* __restrict__ Wq, const float* __restrict__ Wkv,
                             const float* __restrict__ Wo, const float* __restrict__ W1,
                             const float* __restrict__ W2, bf16* __restrict__ dst) {
  int idx = (blockIdx.x * blockDim.x + threadIdx.x) * 4;
  if (idx >= SEG_END) return;
  const float* src;
  if (idx < SEG_QKV) {
    src = (idx < 589824) ? Wq + idx : Wkv + (idx - 589824);
  } else if (idx < SEG_WO) {
    src = Wo + (idx - SEG_QKV);
  } else if (idx < SEG_W1) {
    src = W1 + (idx - SEG_WO);
  } else {
    src = W2 + (idx - SEG_W1);
  }
  float4 f = *(const float4*)src;
  bf16 b0 = f2b(f.x), b1 = f2b(f.y), b2 = f2b(f.z), b3 = f2b(f.w);
  unsigned short o[4];
  o[0] = *(unsigned short*)&b0; o[1] = *(unsigned short*)&b1;
  o[2] = *(unsigned short*)&b2; o[3] = *(unsigned short*)&b3;
  *(uint2*)((unsigned short*)dst + idx) = *(uint2*)o;
}

// C[M,N] = A[M,K] @ W[N,K]^T (+bias)(+relu). bf16 in, fp32 acc, OT out.
// 256 thr = 4 waves (2x2). BN=128, BM=32*MREP (128 or 64), BK=32.
// Double-buffered 2-phase K-loop: stage(t+1) issued BEFORE compute(t).
// SPLITK>1: blockIdx.z selects K-chunk; fp32 partials reduced by gemmred_kernel.
template <int MREP, int RELU, int SPLITK, typename OT>
__global__ __launch_bounds__(256) void gemm_async(const bf16* __restrict__ A,
                                                  const bf16* __restrict__ W,
                                                  const float* __restrict__ bias,
                                                  OT* __restrict__ C,
                                                  int ldc, int K) {
  constexpr int BM = MREP * 32;
  __shared__ __align__(16) unsigned short Asm[2][BM * 32];
  __shared__ __align__(16) unsigned short Bsm[2][128 * 32];
  const int t = threadIdx.x;
  const int w = t >> 6, lane = t & 63;
  const int col = lane & 15, quad = lane >> 4;
  const int wm = w >> 1, wn = w & 1;
  const int m0 = blockIdx.y * BM, n0 = blockIdx.x * 128;
  const int Kc = K / SPLITK;
  const int kbeg = (SPLITK > 1) ? blockIdx.z * Kc : 0;

  const bf16* aSrc = A + (size_t)(m0 + w * 16 + col) * K + kbeg + quad * 8;
  const bf16* bSrc = W + (size_t)(n0 + w * 16 + col) * K + kbeg + quad * 8;

  const f32x4 zf = {0.0f, 0.0f, 0.0f, 0.0f};
  f32x4 acc[MREP][4];
  #pragma unroll
  for (int mt = 0; mt < MREP; mt++)
    #pragma unroll
    for (int nt = 0; nt < 4; nt++) acc[mt][nt] = zf;

  // prologue: stage tile 0 into buf 0
  #pragma unroll
  for (int i = 0; i < MREP / 2; i++)
    async_cp16(aSrc + (size_t)i * 64 * K, &Asm[0][i * 2048 + w * 512]);
  #pragma unroll
  for (int i = 0; i < 2; i++)
    async_cp16(bSrc + (size_t)i * 64 * K, &Bsm[0][i * 2048 + w * 512]);
  __syncthreads();                 // vmcnt(0) drain before barrier

  int cur = 0;
  for (int kk = 32; kk < Kc; kk += 32) {
    #pragma unroll
    for (int i = 0; i < MREP / 2; i++)
      async_cp16(aSrc + kk + (size_t)i * 64 * K, &Asm[cur ^ 1][i * 2048 + w * 512]);
    #pragma unroll
    for (int i = 0; i < 2; i++)
      async_cp16(bSrc + kk + (size_t)i * 64 * K, &Bsm[cur ^ 1][i * 2048 + w * 512]);
    bf16x8 af[MREP], bfr[4];
    #pragma unroll
    for (int mt = 0; mt < MREP; mt++)
      af[mt] = *(const bf16x8*)&Asm[cur][(wm * MREP + mt) * 512 + lane * 8];
    #pragma unroll
    for (int nt = 0; nt < 4; nt++)
      bfr[nt] = *(const bf16x8*)&Bsm[cur][(wn * 4 + nt) * 512 + lane * 8];
    #pragma unroll
    for (int mt = 0; mt < MREP; mt++)
      #pragma unroll
      for (int nt = 0; nt < 4; nt++)
        acc[mt][nt] = __builtin_amdgcn_mfma_f32_16x16x32_bf16(af[mt], bfr[nt],
                                                              acc[mt][nt], 0, 0, 0);
    __syncthreads();               // drains next-tile stage; protects buf reuse
    cur ^= 1;
  }
  {
    bf16x8 af[MREP], bfr[4];
    #pragma unroll
    for (int mt = 0; mt < MREP; mt++)
      af[mt] = *(const bf16x8*)&Asm[cur][(wm * MREP + mt) * 512 + lane * 8];
    #pragma unroll
    for (int nt = 0; nt < 4; nt++)
      bfr[nt] = *(const bf16x8*)&Bsm[cur][(wn * 4 + nt) * 512 + lane * 8];
    #pragma unroll
    for (int mt = 0; mt < MREP; mt++)
      #pragma unroll
      for (int nt = 0; nt < 4; nt++)
        acc[mt][nt] = __builtin_amdgcn_mfma_f32_16x16x32_bf16(af[mt], bfr[nt],
                                                              acc[mt][nt], 0, 0, 0);
  }

  OT* Cb = C;
  if (SPLITK > 1)
    Cb = C + (size_t)blockIdx.z * gridDim.y * BM * ldc;
  #pragma unroll
  for (int nt = 0; nt < 4; nt++) {
    const int colg = n0 + wn * 64 + nt * 16 + col;
    const float bv = bias ? bias[colg] : 0.0f;
    #pragma unroll
    for (int mt = 0; mt < MREP; mt++) {
      #pragma unroll
      for (int r = 0; r < 4; r++) {
        const int row = m0 + wm * (MREP * 16) + mt * 16 + quad * 4 + r;
        float val = acc[mt][nt][r] + bv;
        if (RELU) val = fmaxf(val, 0.0f);
        if constexpr (__is_same(OT, float)) {
          Cb[(size_t)row * ldc + colg] = val;
        } else {
          Cb[(size_t)row * ldc + colg] = f2b(val);
        }
      }
    }
  }
}

// out[i] = f2b( sum_z part[z][i] + bias[i % N] )  (optional relu)
template <int NSLICE, int RELU>
__global__ void gemmred_kernel(const float* __restrict__ part, const float* __restrict__ bias,
                               bf16* __restrict__ out, int N, size_t MN) {
  size_t i4 = ((size_t)blockIdx.x * blockDim.x + threadIdx.x) * 4;
  if (i4 >= MN) return;
  float4 a = *(const float4*)(part + i4);
  #pragma unroll
  for (int z = 1; z < NSLICE; z++) {
    float4 p = *(const float4*)(part + (size_t)z * MN + i4);
    a.x += p.x; a.y += p.y; a.z += p.z; a.w += p.w;
  }
  if (bias) {
    int colb = (int)(i4 % N);
    a.x += bias[colb]; a.y += bias[colb + 1]; a.z += bias[colb + 2]; a.w += bias[colb + 3];
  }
  if (RELU) {
    a.x = fmaxf(a.x, 0.0f); a.y = fmaxf(a.y, 0.0f);
    a.z = fmaxf(a.z, 0.0f); a.w = fmaxf(a.w, 0.0f);
  }
  bf16 b0 = f2b(a.x), b1 = f2b(a.y), b2 = f2b(a.z), b3 = f2b(a.w);
  unsigned short o[4];
  o[0] = *(unsigned short*)&b0; o[1] = *(unsigned short*)&b1;
  o[2] = *(unsigned short*)&b2; o[3] = *(unsigned short*)&b3;
  *(uint2*)((unsigned short*)out + i4) = *(uint2*)o;
}

// Flash attention with MFMA. Block = 256 thr = 4 waves; one 64-row Q tile per (b,n).
// SPLIT==2: blockIdx.z halves the causal KV range (flash-decoding style);
// partial o/l (bf16) -> po0/po1, row stats m,l (fp32) -> pml[z][2][NROW];
// attn_comb merges. SPLIT==1: writes att directly.
// K/V tile jt+1 prefetched into regs while computing tile jt (T14).
template <int SPLIT>
__global__ __launch_bounds__(256) void attn_flash(const bf16* __restrict__ q,
                                                  const bf16* __restrict__ k,
                                                  const bf16* __restrict__ v,
                                                  bf16* __restrict__ att,
                                                  bf16* __restrict__ po0,
                                                  bf16* __restrict__ po1,
                                                  float* __restrict__ pml) {
  const int it = blockIdx.x;       // q-tile index (16)
  const int bn = blockIdx.y;       // b*NH+n (48)
  const int b = bn / NH, n = bn % NH;
  const int t = threadIdx.x;
  const int w = t >> 6, lane = t & 63;
  const int col = lane & 15, quad = lane >> 4;
  const int i0 = it * 64;

  int jbeg = 0, jend = it + 1;
  if (SPLIT == 2) {
    const int half = (it + 2) >> 1;
    if (blockIdx.z == 0) jend = half; else jbeg = half;
    if (jbeg >= jend) return;      // it==0, z==1: nothing to do
  }

  __shared__ __align__(16) unsigned short Kt[64 * 72];  // K[j][d], row stride 72
  __shared__ __align__(16) unsigned short Vt[64 * 72];  // V^T[d][j]
  __shared__ __align__(16) unsigned short Pw[64 * 72];  // per-wave P rows

  const unsigned short* qp = (const unsigned short*)q;
  const unsigned short* kp = (const unsigned short*)k;
  const unsigned short* vp = (const unsigned short*)v;

  bf16x8 aq[2];
  {
    size_t qb = ((size_t)(i0 + w * 16 + col) * B + b) * QS + n * DH + quad * 8;
    aq[0] = *(const bf16x8*)(qp + qb);
    aq[1] = *(const bf16x8*)(qp + qb + 32);
  }

  const f32x4 zf = {0.0f, 0.0f, 0.0f, 0.0f};
  float mrow[4], lrow[4];
  f32x4 o[4];
  #pragma unroll
  for (int r = 0; r < 4; r++) { mrow[r] = -1e30f; lrow[r] = 0.0f; }
  #pragma unroll
  for (int db = 0; db < 4; db++) o[db] = zf;

  const int jj = t >> 2;           // 0..63 (staging row)
  const int d0 = (t & 3) << 4;     // 0,16,32,48

  // prologue: load first K/V tile into regs
  uint4 rk0, rk1, rv0, rv1;
  {
    size_t gb = ((size_t)(jbeg * 64 + jj) * B + b) * QS + n * DH + d0;
    rk0 = *(const uint4*)(kp + gb); rk1 = *(const uint4*)(kp + gb + 8);
    rv0 = *(const uint4*)(vp + gb); rv1 = *(const uint4*)(vp + gb + 8);
  }

  for (int jt = jbeg; jt < jend; jt++) {
    const int j0 = jt * 64;
    __syncthreads();               // prior iteration's LDS reads complete
    {
      *(uint4*)&Kt[jj * 72 + d0] = rk0;
      *(uint4*)&Kt[jj * 72 + d0 + 8] = rk1;
      unsigned short tv[16];
      *(uint4*)tv = rv0;
      *(uint4*)(tv + 8) = rv1;
      #pragma unroll
      for (int x = 0; x < 16; x++) Vt[(d0 + x) * 72 + jj] = tv[x];
    }
    __syncthreads();
    // prefetch next tile (latency hides under compute below)
    if (jt + 1 < jend) {
      size_t gb = ((size_t)((jt + 1) * 64 + jj) * B + b) * QS + n * DH + d0;
      rk0 = *(const uint4*)(kp + gb); rk1 = *(const uint4*)(kp + gb + 8);
      rv0 = *(const uint4*)(vp + gb); rv1 = *(const uint4*)(vp + gb + 8);
    }

    f32x4 sf[4];
    #pragma unroll
    for (int nb = 0; nb < 4; nb++) sf[nb] = zf;
    #pragma unroll
    for (int ks = 0; ks < 2; ks++) {
      #pragma unroll
      for (int nb = 0; nb < 4; nb++) {
        bf16x8 kb = *(const bf16x8*)&Kt[(nb * 16 + col) * 72 + ks * 32 + quad * 8];
        sf[nb] = __builtin_amdgcn_mfma_f32_16x16x32_bf16(aq[ks], kb, sf[nb], 0, 0, 0);
      }
    }

    const bool diag = (jt == it);
    #pragma unroll
    for (int r = 0; r < 4; r++) {
      const int irow = i0 + w * 16 + quad * 4 + r;
      float sv[4];
      #pragma unroll
      for (int nb = 0; nb < 4; nb++) {
        float s = sf[nb][r] * 0.125f;
        if (diag && (j0 + nb * 16 + col) > irow) s = -1e30f;
        sv[nb] = s;
      }
      float rm = fmaxf(fmaxf(sv[0], sv[1]), fmaxf(sv[2], sv[3]));
      #pragma unroll
      for (int off = 8; off > 0; off >>= 1) rm = fmaxf(rm, __shfl_xor(rm, off, 64));
      const float mn = fmaxf(mrow[r], rm);
      const float alpha = __expf(mrow[r] - mn);
      mrow[r] = mn;
      float ps = 0.0f;
      #pragma unroll
      for (int nb = 0; nb < 4; nb++) {
        float p = __expf(sv[nb] - mn);
        ps += p;
        bf16 hb = f2b(p);
        Pw[(w * 16 + quad * 4 + r) * 72 + nb * 16 + col] = *(unsigned short*)&hb;
      }
      #pragma unroll
      for (int off = 8; off > 0; off >>= 1) ps += __shfl_xor(ps, off, 64);
      lrow[r] = lrow[r] * alpha + ps;
      #pragma unroll
      for (int db = 0; db < 4; db++) o[db][r] *= alpha;
    }

    #pragma unroll
    for (int ks = 0; ks < 2; ks++) {
      bf16x8 pa = *(const bf16x8*)&Pw[(w * 16 + col) * 72 + ks * 32 + quad * 8];
      #pragma unroll
      for (int db = 0; db < 4; db++) {
        bf16x8 vb = *(const bf16x8*)&Vt[(db * 16 + col) * 72 + ks * 32 + quad * 8];
        o[db] = __builtin_amdgcn_mfma_f32_16x16x32_bf16(pa, vb, o[db], 0, 0, 0);
      }
    }
  }

  if (SPLIT == 1) {
    unsigned short* ap = (unsigned short*)att;
    #pragma unroll
    for (int r = 0; r < 4; r++) {
      const int irow = i0 + w * 16 + quad * 4 + r;
      const float inv = 1.0f / lrow[r];
      size_t ob = ((size_t)irow * B + b) * Dm + n * DH + col;
      #pragma unroll
      for (int db = 0; db < 4; db++) {
        bf16 hb = f2b(o[db][r] * inv);
        ap[ob + db * 16] = *(unsigned short*)&hb;
      }
    }
  } else {
    unsigned short* pp = (unsigned short*)(blockIdx.z ? po1 : po0);
    float* pm = pml + (size_t)blockIdx.z * 2 * NROW;
    float* pl = pm + NROW;
    #pragma unroll
    for (int r = 0; r < 4; r++) {
      const int irow = i0 + w * 16 + quad * 4 + r;
      const float inv = 1.0f / lrow[r];
      size_t ob = ((size_t)irow * B + b) * Dm + n * DH + col;
      #pragma unroll
      for (int db = 0; db < 4; db++) {
        bf16 hb = f2b(o[db][r] * inv);
        pp[ob + db * 16] = *(unsigned short*)&hb;
      }
      if (col == 0) {
        int rix = (irow * B + b) * NH + n;
        pm[rix] = mrow[r];
        pl[rix] = lrow[r];
      }
    }
  }
}

// merge the two KV-split partials: att = [sum_z e^{m_z-M} l_z (o_z/l_z)] / [sum e^{m_z-M} l_z]
__global__ void attn_comb(const bf16* __restrict__ po0, const bf16* __restrict__ po1,
                          const float* __restrict__ pml, bf16* __restrict__ att) {
  size_t i4 = ((size_t)blockIdx.x * blockDim.x + threadIdx.x) * 4;
  if (i4 >= (size_t)S * B * Dm) return;
  int sb = (int)(i4 / Dm);            // srow*B + b
  int dd = (int)(i4 % Dm);
  int srow = sb / B;
  int it = srow >> 6;
  uint2 a0 = *(const uint2*)((const unsigned short*)po0 + i4);
  if (it == 0) {                       // only z=0 partial exists
    *(uint2*)((unsigned short*)att + i4) = a0;
    return;
  }
  uint2 a1 = *(const uint2*)((const unsigned short*)po1 + i4);
  int rix = sb * NH + (dd >> 6);
  float m0 = pml[rix],            l0 = pml[NROW + rix];
  float m1 = pml[2 * NROW + rix], l1 = pml[3 * NROW + rix];
  float M = fmaxf(m0, m1);
  float w0 = l0 * __expf(m0 - M), w1 = l1 * __expf(m1 - M);
  float inv = 1.0f / (w0 + w1);
  const unsigned short* p0 = (const unsigned short*)&a0;
  const unsigned short* p1 = (const unsigned short*)&a1;
  unsigned short o[4];
  #pragma unroll
  for (int j = 0; j < 4; j++) {
    float val = (w0 * b2f(*(const bf16*)&p0[j]) + w1 * b2f(*(const bf16*)&p1[j])) * inv;
    bf16 hb = f2b(val);
    o[j] = *(unsigned short*)&hb;
  }
  *(uint2*)((unsigned short*)att + i4) = *(uint2*)o;
}

// MFMA meminfer: per (b,n), num[s,v] = cQ[s,:]@mem[:,v], den[s] = cQ[s,:]@mnorm
// (and same with cK for delta). B operand = mem^T in fragment layout, with a 5th
// 16-row tile whose row 0 is mnorm -> dens fall out of the same MFMAs (col 64).
__global__ __launch_bounds__(256) void meminfer_mfma(const bf16* __restrict__ qkv,
                                                     const float* __restrict__ mem,
                                                     const float* __restrict__ mnorm,
                                                     bf16* __restrict__ att,
                                                     bf16* __restrict__ vd) {
  const int s0 = blockIdx.x * 64;
  const int bn = blockIdx.y;
  const int b = bn / NH, n = bn % NH;
  const int t = threadIdx.x;
  const int w = t >> 6, lane = t & 63;
  const int col = lane & 15, quad = lane >> 4;

  __shared__ __align__(16) unsigned short CQ[4096];   // cQ rows 0..63, k 0..63
  __shared__ __align__(16) unsigned short CK[4096];   // cK rows
  __shared__ __align__(16) unsigned short Bm[5120];   // mem^T (4 tiles) + mnorm tile

  const unsigned short* qp = (const unsigned short*)qkv;

  {
    int r = t >> 2;
    int k0 = (t & 3) * 16;
    size_t gb = ((size_t)(s0 + r) * B + b) * QS + n * DH + k0;
    int abase = (r >> 4) * 1024 + (k0 >> 5) * 512 + ((k0 & 31) >> 3) * 128 + (r & 15) * 8;
    unsigned short tq[16], tv[16], oq[16], ov[16];
    *(uint4*)tq = *(const uint4*)(qp + gb);
    *(uint4*)(tq + 8) = *(const uint4*)(qp + gb + 8);
    *(uint4*)tv = *(const uint4*)(qp + gb + 1536);
    *(uint4*)(tv + 8) = *(const uint4*)(qp + gb + 1536 + 8);
    #pragma unroll
    for (int i = 0; i < 16; i++) {
      float fq = b2f(*(const bf16*)&tq[i]);
      float fv = b2f(*(const bf16*)&tv[i]);
      float eq = fq > 0.0f ? fq + 1.0f : __expf(fq);
      float ev = fv > 0.0f ? fv + 1.0f : __expf(fv);
      bf16 bq = f2b(eq), bv2 = f2b(ev);
      oq[i] = *(unsigned short*)&bq;
      ov[i] = *(unsigned short*)&bv2;
    }
    *(bf16x8*)&CQ[abase] = *(bf16x8*)oq;
    *(bf16x8*)&CQ[abase + 128] = *(bf16x8*)(oq + 8);
    *(bf16x8*)&CK[abase] = *(bf16x8*)ov;
    *(bf16x8*)&CK[abase + 128] = *(bf16x8*)(ov + 8);
  }
  {
    int v = t & 63, kb = (t >> 6) * 16;
    const float* mp = mem + (size_t)bn * DH * DH;
    #pragma unroll
    for (int i = 0; i < 16; i++) {
      int k = kb + i;
      bf16 mb = f2b(mp[(size_t)k * DH + v]);
      int addr = (v >> 4) * 1024 + (k >> 5) * 512 + ((k & 31) >> 3) * 128 + (v & 15) * 8 + (k & 7);
      Bm[addr] = *(unsigned short*)&mb;
    }
  }
  {
    int a = t * 4;
    int m = (a >> 3) & 15;
    int kk = (a >> 9) * 32 + ((a >> 7) & 3) * 8 + (a & 7);
    unsigned short vals[4] = {0, 0, 0, 0};
    if (m == 0) {
      const float* np = mnorm + (size_t)bn * DH;
      #pragma unroll
      for (int j = 0; j < 4; j++) {
        bf16 nb = f2b(np[kk + j]);
        vals[j] = *(unsigned short*)&nb;
      }
    }
    *(uint2*)&Bm[4096 + a] = *(uint2*)vals;
  }
  __syncthreads();

  const f32x4 zf = {0.0f, 0.0f, 0.0f, 0.0f};
  f32x4 aq[5], ak[5];
  #pragma unroll
  for (int nb = 0; nb < 5; nb++) { aq[nb] = zf; ak[nb] = zf; }
  #pragma unroll
  for (int ks = 0; ks < 2; ks++) {
    bf16x8 fq = *(const bf16x8*)&CQ[w * 1024 + ks * 512 + lane * 8];
    bf16x8 fk = *(const bf16x8*)&CK[w * 1024 + ks * 512 + lane * 8];
    #pragma unroll
    for (int nb = 0; nb < 5; nb++) {
      bf16x8 bm = *(const bf16x8*)&Bm[nb * 1024 + ks * 512 + lane * 8];
      aq[nb] = __builtin_amdgcn_mfma_f32_16x16x32_bf16(fq, bm, aq[nb], 0, 0, 0);
      ak[nb] = __builtin_amdgcn_mfma_f32_16x16x32_bf16(fk, bm, ak[nb], 0, 0, 0);
    }
  }

  const float gate = 1.0f / (1.0f + expf(-0.01f));
  unsigned short* ap = (unsigned short*)att;
  unsigned short* vp2 = (unsigned short*)vd;
  #pragma unroll
  for (int r = 0; r < 4; r++) {
    const int srow = s0 + w * 16 + quad * 4 + r;
    const float denq = __shfl(aq[4][r], lane & 48, 64);
    const float denk = __shfl(ak[4][r], lane & 48, 64);
    const size_t bd = ((size_t)srow * B + b) * Dm + n * DH + col;
    const size_t bq = ((size_t)srow * B + b) * QS + 768 + n * DH + col;
    #pragma unroll
    for (int nb = 0; nb < 4; nb++) {
      float content = aq[nb][r] / denq;
      float delta = ak[nb][r] / denk;
      float attv = b2f(*(const bf16*)&ap[bd + nb * 16]);
      bf16 ao = f2b(gate * content + (1.0f - gate) * attv);
      ap[bd + nb * 16] = *(unsigned short*)&ao;
      float kvv = b2f(*(const bf16*)&qp[bq + nb * 16]);
      bf16 vo = f2b(kvv - delta);
      vp2[bd + nb * 16] = *(unsigned short*)&vo;
    }
  }
}

// pass 1: part[c][bn][k*64+v] = sum_{s in chunk c} cK[s,k]*vd[s,v]
__global__ void memupd_kernel(const bf16* __restrict__ qkv, const bf16* __restrict__ vd,
                              float* __restrict__ part, float* __restrict__ pnorm) {
  int bn = blockIdx.x % (B * NH);
  int c = blockIdx.x / (B * NH);
  int b = bn / NH, n = bn % NH;
  int t = threadIdx.x;        // 256
  int k = t >> 2;             // 0..63
  int v0 = (t & 3) * 16;      // 0,16,32,48
  __shared__ float ckl[8][DH];
  __shared__ float vdl[8][DH];
  float acc[16];
  #pragma unroll
  for (int j = 0; j < 16; j++) acc[j] = 0.0f;
  float nsum = 0.0f;
  const int sBeg = c * (S / MU_CHUNK), sEnd = sBeg + S / MU_CHUNK;
  for (int s0 = sBeg; s0 < sEnd; s0 += 8) {
    #pragma unroll
    for (int i2 = 0; i2 < 2; i2++) {
      int idx = t + i2 * 256;
      int sp = idx >> 6, dd = idx & 63;
      int gq = ((s0 + sp) * B + b) * QS + 1536 + n * DH + dd;   // v
      int gd = ((s0 + sp) * B + b) * Dm + n * DH + dd;          // vd
      float vv = b2f(qkv[gq]);
      ckl[sp][dd] = vv > 0.0f ? vv + 1.0f : expf(vv);
      vdl[sp][dd] = b2f(vd[gd]);
    }
    __syncthreads();
    #pragma unroll
    for (int sp = 0; sp < 8; sp++) {
      float cc = ckl[sp][k];
      if ((t & 3) == 0) nsum += cc;
      #pragma unroll
      for (int j = 0; j < 16; j++) acc[j] += cc * vdl[sp][v0 + j];
    }
    __syncthreads();
  }
  float* prow = part + (size_t)c * (B * NH * DH * DH) + (size_t)bn * DH * DH;
  #pragma unroll
  for (int j4 = 0; j4 < 4; j4++) {
    float4 o;
    o.x = acc[j4 * 4 + 0]; o.y = acc[j4 * 4 + 1];
    o.z = acc[j4 * 4 + 2]; o.w = acc[j4 * 4 + 3];
    *(float4*)&prow[k * DH + v0 + j4 * 4] = o;
  }
  if ((t & 3) == 0) pnorm[(size_t)c * (B * NH * DH) + bn * DH + k] = nsum;
}

// pass 2: out_mem = mem + sum_c part[c];  out_norm = mnorm + sum_c pnorm[c]
__global__ void memred_kernel(const float* __restrict__ mem, const float* __restrict__ mnorm,
                              const float* __restrict__ part, const float* __restrict__ pnorm,
                              float* __restrict__ out_mem, float* __restrict__ out_norm) {
  const int MEMN = B * NH * DH * DH;   // 786432
  int i = blockIdx.x * blockDim.x + threadIdx.x;
  if (i < MEMN / 4) {
    int i4 = i * 4;
    float4 a = *(const float4*)(mem + i4);
    #pragma unroll
    for (int c = 0; c < MU_CHUNK; c++) {
      float4 p = *(const float4*)(part + (size_t)c * MEMN + i4);
      a.x += p.x; a.y += p.y; a.z += p.z; a.w += p.w;
    }
    *(float4*)(out_mem + i4) = a;
  } else {
    int j4 = (i - MEMN / 4) * 4;
    if (j4 < B * NH * DH) {
      float4 a = *(const float4*)(mnorm + j4);
      #pragma unroll
      for (int c = 0; c < MU_CHUNK; c++) {
        float4 p = *(const float4*)(pnorm + (size_t)c * (B * NH * DH) + j4);
        a.x += p.x; a.y += p.y; a.z += p.z; a.w += p.w;
      }
      *(float4*)(out_norm + j4) = a;
    }
  }
}

// out = layer_norm(x + y, g, b); one block per row of 768. fp32 and/or bf16 out.
template <typename TX, typename TY>
__global__ void addln_kernel(const TX* __restrict__ x, const TY* __restrict__ y,
                             const float* __restrict__ g, const float* __restrict__ bb,
                             float* __restrict__ outf, bf16* __restrict__ outb) {
  int row = blockIdx.x;
  int t = threadIdx.x;      // 256
  float vals[3];
  float sum = 0.0f, sq = 0.0f;
  #pragma unroll
  for (int i = 0; i < 3; i++) {
    size_t idx = (size_t)row * Dm + t + i * 256;
    float vv = ldv(x, idx) + ldv(y, idx);
    vals[i] = vv;
    sum += vv;
    sq += vv * vv;
  }
  sum = wave_sum(sum);
  sq = wave_sum(sq);
  __shared__ float s1[4], s2[4];
  int w = t >> 6, lane = t & 63;
  if (lane == 0) { s1[w] = sum; s2[w] = sq; }
  __syncthreads();
  if (t == 0) {
    s1[0] = s1[0] + s1[1] + s1[2] + s1[3];
    s2[0] = s2[0] + s2[1] + s2[2] + s2[3];
  }
  __syncthreads();
  sum = s1[0]; sq = s2[0];
  float mu = sum / 768.0f;
  float var = sq / 768.0f - mu * mu;
  float rs = rsqrtf(var + 1e-5f);
  #pragma unroll
  for (int i = 0; i < 3; i++) {
    int d = t + i * 256;
    float o = (vals[i] - mu) * rs * g[d] + bb[d];
    size_t idx = (size_t)row * Dm + d;
    if (outf) outf[idx] = o;
    if (outb) outb[idx] = f2b(o);
  }
}

extern "C" void kernel_launch(void* const* d_in, const int* in_sizes, int n_in,
                              void* d_out, int out_size, void* d_ws, size_t ws_size,
                              hipStream_t stream) {
  (void)in_sizes; (void)n_in; (void)out_size;
  const int*   inp   = (const int*)d_in[0];
  const float* wemb  = (const float*)d_in[1];
  const float* Wq    = (const float*)d_in[2];
  const float* Wkv   = (const float*)d_in[3];
  const float* Wo    = (const float*)d_in[4];
  const float* ln1g  = (const float*)d_in[5];
  const float* ln1b  = (const float*)d_in[6];
  const float* fW1   = (const float*)d_in[7];
  const float* fb1   = (const float*)d_in[8];
  const float* fW2   = (const float*)d_in[9];
  const float* fb2   = (const float*)d_in[10];
  const float* ln2g  = (const float*)d_in[11];
  const float* ln2b  = (const float*)d_in[12];
  const float* mem   = (const float*)d_in[13];
  const float* mnorm = (const float*)d_in[14];

  const size_t SBD = (size_t)S * B * Dm;   // 3,145,728

  bf16* ws   = (bf16*)d_ws;
  bf16* qkv  = ws;              // slots 0-2: fused qkv, [4096][2304]
  bf16* vd   = ws + 3 * SBD;    // slot 3
  bf16* att  = ws + 4 * SBD;    // slot 4 (aliased: h_bf, ff2o — disjoint in time)
  bf16* hbf  = att;
  bf16* ff2o = att;
  bf16* out1 = ws + 5 * SBD;    // slot 5
  bf16* wb   = ws + 6 * SBD;    // bf16 weight pack for current layer
  bf16* ffm  = ws;              // 4*SBD: aliases slots 0-3 (dead by FF1)
  bf16* tmp  = ws;              // Wo-GEMM out (qkv dead after memupd)
  // memupd partials live in out1 slot (dead during memupd).
  float* part  = (float*)out1;
  float* pnorm = (float*)(wb + SEG_END);   // 96 KiB past wb
  // split-K / attn-split scratch past pnorm (25.2 MB)
  float* partg = pnorm + (size_t)MU_CHUNK * B * NH * DH;
  const size_t need = ((size_t)(6 * SBD + SEG_END)) * 2 +
                      ((size_t)MU_CHUNK * B * NH * DH + 2 * SBD) * 4;
  const bool use_splitk = (ws_size >= need);
  // attn KV-split partials: po0 -> vd slot, po1 -> out1 slot (both dead during attn);
  // pml (4*NROW fp32 = 768 KiB) -> partg region (dead during attn).
  bf16* po0 = vd;
  bf16* po1 = out1;
  float* pml = partg;

  float* h    = (float*)d_out;  // residual stream lives in d_out (fp32)
  float* outm = h + SBD;
  float* outn = outm + (size_t)NL * B * NH * DH * DH;

  dim3 b256(256);
  embed_kernel<<<dim3((S * B * Dm + 255) / 256), b256, 0, stream>>>(inp, wemb, h, hbf);

  for (int l = 0; l < NL; l++) {
    convw_kernel<<<dim3(SEG_END / 4 / 256), b256, 0, stream>>>(
        Wq + (size_t)l * Dm * Dm, Wkv + (size_t)l * 2 * Dm * Dm,
        Wo + (size_t)l * Dm * Dm, fW1 + (size_t)l * DI * Dm,
        fW2 + (size_t)l * Dm * DI, wb);
    const bf16* wqkv = wb;
    const bf16* wo_b = wb + SEG_QKV;
    const bf16* w1_b = wb + SEG_WO;
    const bf16* w2_b = wb + SEG_W1;
    const float* mem_l = mem + (size_t)l * B * NH * DH * DH;
    const float* mn_l  = mnorm + (size_t)l * B * NH * DH;
    float* outm_l = outm + (size_t)l * B * NH * DH * DH;
    float* outn_l = outn + (size_t)l * B * NH * DH;

    // fused QKV: M=4096, N=2304, K=768 -> 576 blocks
    gemm_async<4, 0, 1, bf16><<<dim3(QS / 128, 32), b256, 0, stream>>>(
        hbf, wqkv, nullptr, qkv, QS, Dm);

    if (use_splitk) {
      attn_flash<2><<<dim3(S / 64, B * NH, 2), b256, 0, stream>>>(
          qkv, qkv + 768, qkv + 1536, att, po0, po1, pml);
      attn_comb<<<dim3((unsigned)(SBD / 4 / 256)), b256, 0, stream>>>(po0, po1, pml, att);
    } else {
      attn_flash<1><<<dim3(S / 64, B * NH), b256, 0, stream>>>(
          qkv, qkv + 768, qkv + 1536, att, nullptr, nullptr, nullptr);
    }
    meminfer_mfma<<<dim3(S / 64, B * NH), b256, 0, stream>>>(qkv, mem_l, mn_l, att, vd);
    memupd_kernel<<<dim3(B * NH * MU_CHUNK), b256, 0, stream>>>(qkv, vd, part, pnorm);
    memred_kernel<<<dim3(771), b256, 0, stream>>>(mem_l, mn_l, part, pnorm, outm_l, outn_l);

    // Wo: M=4096, N=768, K=768
    if (use_splitk) {
      gemm_async<2, 0, 2, float><<<dim3(Dm / 128, 64, 2), b256, 0, stream>>>(
          att, wo_b, nullptr, partg, Dm, Dm);
      gemmred_kernel<2, 0><<<dim3((unsigned)(SBD / 4 / 256)), b256, 0, stream>>>(
          partg, nullptr, tmp, Dm, SBD);
    } else {
      gemm_async<2, 0, 1, bf16><<<dim3(Dm / 128, 64), b256, 0, stream>>>(
          att, wo_b, nullptr, tmp, Dm, Dm);
    }
    addln_kernel<float, bf16><<<dim3(S * B), b256, 0, stream>>>(
        h, tmp, ln1g + l * Dm, ln1b + l * Dm, nullptr, out1);

    // FF1: M=4096, N=3072, K=768 -> 768 blocks
    gemm_async<4, 1, 1, bf16><<<dim3(DI / 128, 32), b256, 0, stream>>>(
        out1, w1_b, fb1 + (size_t)l * DI, ffm, DI, Dm);
    // FF2: M=4096, N=768, K=3072
    if (use_splitk) {
      gemm_async<2, 0, 2, float><<<dim3(Dm / 128, 64, 2), b256, 0, stream>>>(
          ffm, w2_b, nullptr, partg, Dm, DI);
      gemmred_kernel<2, 0><<<dim3((unsigned)(SBD / 4 / 256)), b256, 0, stream>>>(
          partg, fb2 + (size_t)l * Dm, ff2o, Dm, SBD);
    } else {
      gemm_async<2, 0, 1, bf16><<<dim3(Dm / 128, 64), b256, 0, stream>>>(
          ffm, w2_b, fb2 + (size_t)l * Dm, ff2o, Dm, DI);
    }
    addln_kernel<bf16, bf16><<<dim3(S * B), b256, 0, stream>>>(
        out1, ff2o, ln2g + l * Dm, ln2b + l * Dm, h, hbf);
  }
}

// Round 7
// 1284.983 us; speedup vs baseline: 1.0413x; 1.0413x over previous
//
#include <hip/hip_runtime.h>
#include <hip/hip_bf16.h>
#include <math.h>

#define S 1024
#define B 4
#define Dm 768
#define NH 12
#define DH 64
#define NL 4
#define DI 3072
#define QS 2304   // row stride of fused qkv activation buffer
#define MU_CHUNK 8   // S-dim split for memupd
#define NROW (S * B * NH)   // 49152 attention rows

typedef __hip_bfloat16 bf16;
typedef short bf16x8 __attribute__((ext_vector_type(8)));
typedef float f32x4 __attribute__((ext_vector_type(4)));

__device__ __forceinline__ float b2f(bf16 x) { return __bfloat162float(x); }
__device__ __forceinline__ bf16 f2b(float x) { return __float2bfloat16(x); }

__device__ __forceinline__ float ldv(const float* p, size_t i) { return p[i]; }
__device__ __forceinline__ float ldv(const bf16* p, size_t i) { return b2f(p[i]); }

__device__ __forceinline__ float wave_sum(float x) {
  #pragma unroll
  for (int off = 32; off > 0; off >>= 1) x += __shfl_xor(x, off, 64);
  return x;
}

// async 16B global -> LDS DMA. LDS dest = wave-uniform base + lane*16.
typedef const __attribute__((address_space(1))) unsigned int guint;
typedef __attribute__((address_space(3))) unsigned int luint;
__device__ __forceinline__ void async_cp16(const void* g, void* l) {
  __builtin_amdgcn_global_load_lds((guint*)g, (luint*)l, 16, 0, 0);
}

// h[s,b,d] = word_emb[inp[s,b], d] * sqrt(D) + pos_emb(s, d); fp32 + bf16 copies
__global__ void embed_kernel(const int* __restrict__ inp, const float* __restrict__ wemb,
                             float* __restrict__ h, bf16* __restrict__ hb) {
  int idx = blockIdx.x * blockDim.x + threadIdx.x;
  if (idx >= S * B * Dm) return;
  int d = idx % Dm;
  int sb = idx / Dm;
  int b = sb % B;
  int s = sb / B;
  int tok = inp[s * B + b];
  float e = wemb[(size_t)tok * Dm + d] * 27.712812921102035f; // sqrt(768)
  float ps = (float)(S - 1 - s);
  float pe;
  if (d < Dm / 2) {
    float invf = expf(-(2.0f * (float)d / (float)Dm) * 9.210340371976184f); // ln(10000)
    pe = sinf(ps * invf);
  } else {
    int j = d - Dm / 2;
    float invf = expf(-(2.0f * (float)j / (float)Dm) * 9.210340371976184f);
    pe = cosf(ps * invf);
  }
  float val = e + pe;
  h[idx] = val;
  hb[idx] = f2b(val);
}

// pack one layer's weights to bf16 into wb:
//   [qkv 2304x768 | wo 768x768 | w1 3072x768 | w2 768x3072]  (all B^T, K contiguous)
#define SEG_QKV 1769472
#define SEG_WO  2359296
#define SEG_W1  4718592
#define SEG_END 7077888
__global__ void convw_kernel(const float* __restrict__ Wq, const float* __restrict__ Wkv,
                             const float* __restrict__ Wo, const float* __restrict__ W1,
                             const float* __restrict__ W2, bf16* __restrict__ dst) {
  int idx = (blockIdx.x * blockDim.x + threadIdx.x) * 4;
  if (idx >= SEG_END) return;
  const float* src;
  if (idx < SEG_QKV) {
    src = (idx < 589824) ? Wq + idx : Wkv + (idx - 589824);
  } else if (idx < SEG_WO) {
    src = Wo + (idx - SEG_QKV);
  } else if (idx < SEG_W1) {
    src = W1 + (idx - SEG_WO);
  } else {
    src = W2 + (idx - SEG_W1);
  }
  float4 f = *(const float4*)src;
  bf16 b0 = f2b(f.x), b1 = f2b(f.y), b2 = f2b(f.z), b3 = f2b(f.w);
  unsigned short o[4];
  o[0] = *(unsigned short*)&b0; o[1] = *(unsigned short*)&b1;
  o[2] = *(unsigned short*)&b2; o[3] = *(unsigned short*)&b3;
  *(uint2*)((unsigned short*)dst + idx) = *(uint2*)o;
}

// C[M,N] = A[M,K] @ W[N,K]^T (+bias)(+relu). bf16 in, fp32 acc, OT out.
// 256 thr = 4 waves (2x2). BN=128, BM=32*MREP, BK=32. Double-buffered 2-phase
// K-loop (stage t+1 before compute t). SPLITK>1: blockIdx.z selects K-chunk,
// fp32 partials at slice stride gridDim.y*BM*ldc (reduced by addln_red).
// XCD-aware bijective swizzle (requires nwg%8==0): groups blocks sharing an
// A-row strip onto one XCD so the strip stays L2-resident.
template <int MREP, int RELU, int SPLITK, typename OT>
__global__ __launch_bounds__(256) void gemm_async(const bf16* __restrict__ A,
                                                  const bf16* __restrict__ W,
                                                  const float* __restrict__ bias,
                                                  OT* __restrict__ C,
                                                  int ldc, int K) {
  constexpr int BM = MREP * 32;
  __shared__ __align__(16) unsigned short Asm[2][BM * 32];
  __shared__ __align__(16) unsigned short Bsm[2][128 * 32];
  const int t = threadIdx.x;
  const int w = t >> 6, lane = t & 63;
  const int col = lane & 15, quad = lane >> 4;
  const int wm = w >> 1, wn = w & 1;

  int bx = blockIdx.x, by = blockIdx.y;
  {
    const int nwg = gridDim.x * gridDim.y;
    if ((nwg & 7) == 0) {
      int orig = by * gridDim.x + bx;
      int cpx = nwg >> 3;
      int wg2 = (orig & 7) * cpx + (orig >> 3);
      bx = wg2 % gridDim.x;
      by = wg2 / gridDim.x;
    }
  }
  const int m0 = by * BM, n0 = bx * 128;
  const int Kc = K / SPLITK;
  const int kbeg = (SPLITK > 1) ? blockIdx.z * Kc : 0;

  const bf16* aSrc = A + (size_t)(m0 + w * 16 + col) * K + kbeg + quad * 8;
  const bf16* bSrc = W + (size_t)(n0 + w * 16 + col) * K + kbeg + quad * 8;

  const f32x4 zf = {0.0f, 0.0f, 0.0f, 0.0f};
  f32x4 acc[MREP][4];
  #pragma unroll
  for (int mt = 0; mt < MREP; mt++)
    #pragma unroll
    for (int nt = 0; nt < 4; nt++) acc[mt][nt] = zf;

  // prologue: stage tile 0 into buf 0
  #pragma unroll
  for (int i = 0; i < MREP / 2; i++)
    async_cp16(aSrc + (size_t)i * 64 * K, &Asm[0][i * 2048 + w * 512]);
  #pragma unroll
  for (int i = 0; i < 2; i++)
    async_cp16(bSrc + (size_t)i * 64 * K, &Bsm[0][i * 2048 + w * 512]);
  __syncthreads();                 // vmcnt(0) drain before barrier

  int cur = 0;
  for (int kk = 32; kk < Kc; kk += 32) {
    #pragma unroll
    for (int i = 0; i < MREP / 2; i++)
      async_cp16(aSrc + kk + (size_t)i * 64 * K, &Asm[cur ^ 1][i * 2048 + w * 512]);
    #pragma unroll
    for (int i = 0; i < 2; i++)
      async_cp16(bSrc + kk + (size_t)i * 64 * K, &Bsm[cur ^ 1][i * 2048 + w * 512]);
    bf16x8 af[MREP], bfr[4];
    #pragma unroll
    for (int mt = 0; mt < MREP; mt++)
      af[mt] = *(const bf16x8*)&Asm[cur][(wm * MREP + mt) * 512 + lane * 8];
    #pragma unroll
    for (int nt = 0; nt < 4; nt++)
      bfr[nt] = *(const bf16x8*)&Bsm[cur][(wn * 4 + nt) * 512 + lane * 8];
    #pragma unroll
    for (int mt = 0; mt < MREP; mt++)
      #pragma unroll
      for (int nt = 0; nt < 4; nt++)
        acc[mt][nt] = __builtin_amdgcn_mfma_f32_16x16x32_bf16(af[mt], bfr[nt],
                                                              acc[mt][nt], 0, 0, 0);
    __syncthreads();               // drains next-tile stage; protects buf reuse
    cur ^= 1;
  }
  {
    bf16x8 af[MREP], bfr[4];
    #pragma unroll
    for (int mt = 0; mt < MREP; mt++)
      af[mt] = *(const bf16x8*)&Asm[cur][(wm * MREP + mt) * 512 + lane * 8];
    #pragma unroll
    for (int nt = 0; nt < 4; nt++)
      bfr[nt] = *(const bf16x8*)&Bsm[cur][(wn * 4 + nt) * 512 + lane * 8];
    #pragma unroll
    for (int mt = 0; mt < MREP; mt++)
      #pragma unroll
      for (int nt = 0; nt < 4; nt++)
        acc[mt][nt] = __builtin_amdgcn_mfma_f32_16x16x32_bf16(af[mt], bfr[nt],
                                                              acc[mt][nt], 0, 0, 0);
  }

  OT* Cb = C;
  if (SPLITK > 1)
    Cb = C + (size_t)blockIdx.z * gridDim.y * BM * ldc;
  #pragma unroll
  for (int nt = 0; nt < 4; nt++) {
    const int colg = n0 + wn * 64 + nt * 16 + col;
    const float bv = bias ? bias[colg] : 0.0f;
    #pragma unroll
    for (int mt = 0; mt < MREP; mt++) {
      #pragma unroll
      for (int r = 0; r < 4; r++) {
        const int row = m0 + wm * (MREP * 16) + mt * 16 + quad * 4 + r;
        float val = acc[mt][nt][r] + bv;
        if (RELU) val = fmaxf(val, 0.0f);
        if constexpr (__is_same(OT, float)) {
          Cb[(size_t)row * ldc + colg] = val;
        } else {
          Cb[(size_t)row * ldc + colg] = f2b(val);
        }
      }
    }
  }
}

// Flash attention with MFMA. Block = 256 thr = 4 waves; one 64-row Q tile per (b,n).
// SPLIT==2: blockIdx.z halves the causal KV range; partials merged by attn_comb.
// K/V tile jt+1 prefetched into regs while computing tile jt.
template <int SPLIT>
__global__ __launch_bounds__(256) void attn_flash(const bf16* __restrict__ q,
                                                  const bf16* __restrict__ k,
                                                  const bf16* __restrict__ v,
                                                  bf16* __restrict__ att,
                                                  bf16* __restrict__ po0,
                                                  bf16* __restrict__ po1,
                                                  float* __restrict__ pml) {
  const int it = blockIdx.x;       // q-tile index (16)
  const int bn = blockIdx.y;       // b*NH+n (48)
  const int b = bn / NH, n = bn % NH;
  const int t = threadIdx.x;
  const int w = t >> 6, lane = t & 63;
  const int col = lane & 15, quad = lane >> 4;
  const int i0 = it * 64;

  int jbeg = 0, jend = it + 1;
  if (SPLIT == 2) {
    const int half = (it + 2) >> 1;
    if (blockIdx.z == 0) jend = half; else jbeg = half;
    if (jbeg >= jend) return;      // it==0, z==1: nothing to do
  }

  __shared__ __align__(16) unsigned short Kt[64 * 72];  // K[j][d], row stride 72
  __shared__ __align__(16) unsigned short Vt[64 * 72];  // V^T[d][j]
  __shared__ __align__(16) unsigned short Pw[64 * 72];  // per-wave P rows

  const unsigned short* qp = (const unsigned short*)q;
  const unsigned short* kp = (const unsigned short*)k;
  const unsigned short* vp = (const unsigned short*)v;

  bf16x8 aq[2];
  {
    size_t qb = ((size_t)(i0 + w * 16 + col) * B + b) * QS + n * DH + quad * 8;
    aq[0] = *(const bf16x8*)(qp + qb);
    aq[1] = *(const bf16x8*)(qp + qb + 32);
  }

  const f32x4 zf = {0.0f, 0.0f, 0.0f, 0.0f};
  float mrow[4], lrow[4];
  f32x4 o[4];
  #pragma unroll
  for (int r = 0; r < 4; r++) { mrow[r] = -1e30f; lrow[r] = 0.0f; }
  #pragma unroll
  for (int db = 0; db < 4; db++) o[db] = zf;

  const int jj = t >> 2;           // 0..63 (staging row)
  const int d0 = (t & 3) << 4;     // 0,16,32,48

  // prologue: load first K/V tile into regs
  uint4 rk0, rk1, rv0, rv1;
  {
    size_t gb = ((size_t)(jbeg * 64 + jj) * B + b) * QS + n * DH + d0;
    rk0 = *(const uint4*)(kp + gb); rk1 = *(const uint4*)(kp + gb + 8);
    rv0 = *(const uint4*)(vp + gb); rv1 = *(const uint4*)(vp + gb + 8);
  }

  for (int jt = jbeg; jt < jend; jt++) {
    const int j0 = jt * 64;
    __syncthreads();               // prior iteration's LDS reads complete
    {
      *(uint4*)&Kt[jj * 72 + d0] = rk0;
      *(uint4*)&Kt[jj * 72 + d0 + 8] = rk1;
      unsigned short tv[16];
      *(uint4*)tv = rv0;
      *(uint4*)(tv + 8) = rv1;
      #pragma unroll
      for (int x = 0; x < 16; x++) Vt[(d0 + x) * 72 + jj] = tv[x];
    }
    __syncthreads();
    if (jt + 1 < jend) {
      size_t gb = ((size_t)((jt + 1) * 64 + jj) * B + b) * QS + n * DH + d0;
      rk0 = *(const uint4*)(kp + gb); rk1 = *(const uint4*)(kp + gb + 8);
      rv0 = *(const uint4*)(vp + gb); rv1 = *(const uint4*)(vp + gb + 8);
    }

    f32x4 sf[4];
    #pragma unroll
    for (int nb = 0; nb < 4; nb++) sf[nb] = zf;
    #pragma unroll
    for (int ks = 0; ks < 2; ks++) {
      #pragma unroll
      for (int nb = 0; nb < 4; nb++) {
        bf16x8 kb = *(const bf16x8*)&Kt[(nb * 16 + col) * 72 + ks * 32 + quad * 8];
        sf[nb] = __builtin_amdgcn_mfma_f32_16x16x32_bf16(aq[ks], kb, sf[nb], 0, 0, 0);
      }
    }

    const bool diag = (jt == it);
    #pragma unroll
    for (int r = 0; r < 4; r++) {
      const int irow = i0 + w * 16 + quad * 4 + r;
      float sv[4];
      #pragma unroll
      for (int nb = 0; nb < 4; nb++) {
        float s = sf[nb][r] * 0.125f;
        if (diag && (j0 + nb * 16 + col) > irow) s = -1e30f;
        sv[nb] = s;
      }
      float rm = fmaxf(fmaxf(sv[0], sv[1]), fmaxf(sv[2], sv[3]));
      #pragma unroll
      for (int off = 8; off > 0; off >>= 1) rm = fmaxf(rm, __shfl_xor(rm, off, 64));
      const float mn = fmaxf(mrow[r], rm);
      const float alpha = __expf(mrow[r] - mn);
      mrow[r] = mn;
      float ps = 0.0f;
      #pragma unroll
      for (int nb = 0; nb < 4; nb++) {
        float p = __expf(sv[nb] - mn);
        ps += p;
        bf16 hb = f2b(p);
        Pw[(w * 16 + quad * 4 + r) * 72 + nb * 16 + col] = *(unsigned short*)&hb;
      }
      #pragma unroll
      for (int off = 8; off > 0; off >>= 1) ps += __shfl_xor(ps, off, 64);
      lrow[r] = lrow[r] * alpha + ps;
      #pragma unroll
      for (int db = 0; db < 4; db++) o[db][r] *= alpha;
    }

    #pragma unroll
    for (int ks = 0; ks < 2; ks++) {
      bf16x8 pa = *(const bf16x8*)&Pw[(w * 16 + col) * 72 + ks * 32 + quad * 8];
      #pragma unroll
      for (int db = 0; db < 4; db++) {
        bf16x8 vb = *(const bf16x8*)&Vt[(db * 16 + col) * 72 + ks * 32 + quad * 8];
        o[db] = __builtin_amdgcn_mfma_f32_16x16x32_bf16(pa, vb, o[db], 0, 0, 0);
      }
    }
  }

  if (SPLIT == 1) {
    unsigned short* ap = (unsigned short*)att;
    #pragma unroll
    for (int r = 0; r < 4; r++) {
      const int irow = i0 + w * 16 + quad * 4 + r;
      const float inv = 1.0f / lrow[r];
      size_t ob = ((size_t)irow * B + b) * Dm + n * DH + col;
      #pragma unroll
      for (int db = 0; db < 4; db++) {
        bf16 hb = f2b(o[db][r] * inv);
        ap[ob + db * 16] = *(unsigned short*)&hb;
      }
    }
  } else {
    unsigned short* pp = (unsigned short*)(blockIdx.z ? po1 : po0);
    float* pm = pml + (size_t)blockIdx.z * 2 * NROW;
    float* pl = pm + NROW;
    #pragma unroll
    for (int r = 0; r < 4; r++) {
      const int irow = i0 + w * 16 + quad * 4 + r;
      const float inv = 1.0f / lrow[r];
      size_t ob = ((size_t)irow * B + b) * Dm + n * DH + col;
      #pragma unroll
      for (int db = 0; db < 4; db++) {
        bf16 hb = f2b(o[db][r] * inv);
        pp[ob + db * 16] = *(unsigned short*)&hb;
      }
      if (col == 0) {
        int rix = (irow * B + b) * NH + n;
        pm[rix] = mrow[r];
        pl[rix] = lrow[r];
      }
    }
  }
}

// merge the two KV-split partials
__global__ void attn_comb(const bf16* __restrict__ po0, const bf16* __restrict__ po1,
                          const float* __restrict__ pml, bf16* __restrict__ att) {
  size_t i4 = ((size_t)blockIdx.x * blockDim.x + threadIdx.x) * 4;
  if (i4 >= (size_t)S * B * Dm) return;
  int sb = (int)(i4 / Dm);            // srow*B + b
  int dd = (int)(i4 % Dm);
  int srow = sb / B;
  int it = srow >> 6;
  uint2 a0 = *(const uint2*)((const unsigned short*)po0 + i4);
  if (it == 0) {
    *(uint2*)((unsigned short*)att + i4) = a0;
    return;
  }
  uint2 a1 = *(const uint2*)((const unsigned short*)po1 + i4);
  int rix = sb * NH + (dd >> 6);
  float m0 = pml[rix],            l0 = pml[NROW + rix];
  float m1 = pml[2 * NROW + rix], l1 = pml[3 * NROW + rix];
  float M = fmaxf(m0, m1);
  float w0 = l0 * __expf(m0 - M), w1 = l1 * __expf(m1 - M);
  float inv = 1.0f / (w0 + w1);
  const unsigned short* p0 = (const unsigned short*)&a0;
  const unsigned short* p1 = (const unsigned short*)&a1;
  unsigned short o[4];
  #pragma unroll
  for (int j = 0; j < 4; j++) {
    float val = (w0 * b2f(*(const bf16*)&p0[j]) + w1 * b2f(*(const bf16*)&p1[j])) * inv;
    bf16 hb = f2b(val);
    o[j] = *(unsigned short*)&hb;
  }
  *(uint2*)((unsigned short*)att + i4) = *(uint2*)o;
}

// MFMA meminfer: per (b,n), num[s,v] = cQ[s,:]@mem[:,v], den[s] = cQ[s,:]@mnorm
// via a 5th 16-row B-tile holding mnorm.
__global__ __launch_bounds__(256) void meminfer_mfma(const bf16* __restrict__ qkv,
                                                     const float* __restrict__ mem,
                                                     const float* __restrict__ mnorm,
                                                     bf16* __restrict__ att,
                                                     bf16* __restrict__ vd) {
  const int s0 = blockIdx.x * 64;
  const int bn = blockIdx.y;
  const int b = bn / NH, n = bn % NH;
  const int t = threadIdx.x;
  const int w = t >> 6, lane = t & 63;
  const int col = lane & 15, quad = lane >> 4;

  __shared__ __align__(16) unsigned short CQ[4096];
  __shared__ __align__(16) unsigned short CK[4096];
  __shared__ __align__(16) unsigned short Bm[5120];

  const unsigned short* qp = (const unsigned short*)qkv;

  {
    int r = t >> 2;
    int k0 = (t & 3) * 16;
    size_t gb = ((size_t)(s0 + r) * B + b) * QS + n * DH + k0;
    int abase = (r >> 4) * 1024 + (k0 >> 5) * 512 + ((k0 & 31) >> 3) * 128 + (r & 15) * 8;
    unsigned short tq[16], tv[16], oq[16], ov[16];
    *(uint4*)tq = *(const uint4*)(qp + gb);
    *(uint4*)(tq + 8) = *(const uint4*)(qp + gb + 8);
    *(uint4*)tv = *(const uint4*)(qp + gb + 1536);
    *(uint4*)(tv + 8) = *(const uint4*)(qp + gb + 1536 + 8);
    #pragma unroll
    for (int i = 0; i < 16; i++) {
      float fq = b2f(*(const bf16*)&tq[i]);
      float fv = b2f(*(const bf16*)&tv[i]);
      float eq = fq > 0.0f ? fq + 1.0f : __expf(fq);
      float ev = fv > 0.0f ? fv + 1.0f : __expf(fv);
      bf16 bq = f2b(eq), bv2 = f2b(ev);
      oq[i] = *(unsigned short*)&bq;
      ov[i] = *(unsigned short*)&bv2;
    }
    *(bf16x8*)&CQ[abase] = *(bf16x8*)oq;
    *(bf16x8*)&CQ[abase + 128] = *(bf16x8*)(oq + 8);
    *(bf16x8*)&CK[abase] = *(bf16x8*)ov;
    *(bf16x8*)&CK[abase + 128] = *(bf16x8*)(ov + 8);
  }
  {
    int v = t & 63, kb = (t >> 6) * 16;
    const float* mp = mem + (size_t)bn * DH * DH;
    #pragma unroll
    for (int i = 0; i < 16; i++) {
      int k = kb + i;
      bf16 mb = f2b(mp[(size_t)k * DH + v]);
      int addr = (v >> 4) * 1024 + (k >> 5) * 512 + ((k & 31) >> 3) * 128 + (v & 15) * 8 + (k & 7);
      Bm[addr] = *(unsigned short*)&mb;
    }
  }
  {
    int a = t * 4;
    int m = (a >> 3) & 15;
    int kk = (a >> 9) * 32 + ((a >> 7) & 3) * 8 + (a & 7);
    unsigned short vals[4] = {0, 0, 0, 0};
    if (m == 0) {
      const float* np = mnorm + (size_t)bn * DH;
      #pragma unroll
      for (int j = 0; j < 4; j++) {
        bf16 nb = f2b(np[kk + j]);
        vals[j] = *(unsigned short*)&nb;
      }
    }
    *(uint2*)&Bm[4096 + a] = *(uint2*)vals;
  }
  __syncthreads();

  const f32x4 zf = {0.0f, 0.0f, 0.0f, 0.0f};
  f32x4 aq[5], ak[5];
  #pragma unroll
  for (int nb = 0; nb < 5; nb++) { aq[nb] = zf; ak[nb] = zf; }
  #pragma unroll
  for (int ks = 0; ks < 2; ks++) {
    bf16x8 fq = *(const bf16x8*)&CQ[w * 1024 + ks * 512 + lane * 8];
    bf16x8 fk = *(const bf16x8*)&CK[w * 1024 + ks * 512 + lane * 8];
    #pragma unroll
    for (int nb = 0; nb < 5; nb++) {
      bf16x8 bm = *(const bf16x8*)&Bm[nb * 1024 + ks * 512 + lane * 8];
      aq[nb] = __builtin_amdgcn_mfma_f32_16x16x32_bf16(fq, bm, aq[nb], 0, 0, 0);
      ak[nb] = __builtin_amdgcn_mfma_f32_16x16x32_bf16(fk, bm, ak[nb], 0, 0, 0);
    }
  }

  const float gate = 1.0f / (1.0f + expf(-0.01f));
  unsigned short* ap = (unsigned short*)att;
  unsigned short* vp2 = (unsigned short*)vd;
  #pragma unroll
  for (int r = 0; r < 4; r++) {
    const int srow = s0 + w * 16 + quad * 4 + r;
    const float denq = __shfl(aq[4][r], lane & 48, 64);
    const float denk = __shfl(ak[4][r], lane & 48, 64);
    const size_t bd = ((size_t)srow * B + b) * Dm + n * DH + col;
    const size_t bq = ((size_t)srow * B + b) * QS + 768 + n * DH + col;
    #pragma unroll
    for (int nb = 0; nb < 4; nb++) {
      float content = aq[nb][r] / denq;
      float delta = ak[nb][r] / denk;
      float attv = b2f(*(const bf16*)&ap[bd + nb * 16]);
      bf16 ao = f2b(gate * content + (1.0f - gate) * attv);
      ap[bd + nb * 16] = *(unsigned short*)&ao;
      float kvv = b2f(*(const bf16*)&qp[bq + nb * 16]);
      bf16 vo = f2b(kvv - delta);
      vp2[bd + nb * 16] = *(unsigned short*)&vo;
    }
  }
}

// pass 1: part[c][bn][k*64+v] = sum_{s in chunk c} cK[s,k]*vd[s,v]
__global__ void memupd_kernel(const bf16* __restrict__ qkv, const bf16* __restrict__ vd,
                              float* __restrict__ part, float* __restrict__ pnorm) {
  int bn = blockIdx.x % (B * NH);
  int c = blockIdx.x / (B * NH);
  int b = bn / NH, n = bn % NH;
  int t = threadIdx.x;        // 256
  int k = t >> 2;             // 0..63
  int v0 = (t & 3) * 16;      // 0,16,32,48
  __shared__ float ckl[8][DH];
  __shared__ float vdl[8][DH];
  float acc[16];
  #pragma unroll
  for (int j = 0; j < 16; j++) acc[j] = 0.0f;
  float nsum = 0.0f;
  const int sBeg = c * (S / MU_CHUNK), sEnd = sBeg + S / MU_CHUNK;
  for (int s0 = sBeg; s0 < sEnd; s0 += 8) {
    #pragma unroll
    for (int i2 = 0; i2 < 2; i2++) {
      int idx = t + i2 * 256;
      int sp = idx >> 6, dd = idx & 63;
      int gq = ((s0 + sp) * B + b) * QS + 1536 + n * DH + dd;   // v
      int gd = ((s0 + sp) * B + b) * Dm + n * DH + dd;          // vd
      float vv = b2f(qkv[gq]);
      ckl[sp][dd] = vv > 0.0f ? vv + 1.0f : expf(vv);
      vdl[sp][dd] = b2f(vd[gd]);
    }
    __syncthreads();
    #pragma unroll
    for (int sp = 0; sp < 8; sp++) {
      float cc = ckl[sp][k];
      if ((t & 3) == 0) nsum += cc;
      #pragma unroll
      for (int j = 0; j < 16; j++) acc[j] += cc * vdl[sp][v0 + j];
    }
    __syncthreads();
  }
  float* prow = part + (size_t)c * (B * NH * DH * DH) + (size_t)bn * DH * DH;
  #pragma unroll
  for (int j4 = 0; j4 < 4; j4++) {
    float4 o;
    o.x = acc[j4 * 4 + 0]; o.y = acc[j4 * 4 + 1];
    o.z = acc[j4 * 4 + 2]; o.w = acc[j4 * 4 + 3];
    *(float4*)&prow[k * DH + v0 + j4 * 4] = o;
  }
  if ((t & 3) == 0) pnorm[(size_t)c * (B * NH * DH) + bn * DH + k] = nsum;
}

// pass 2: out_mem = mem + sum_c part[c];  out_norm = mnorm + sum_c pnorm[c]
__global__ void memred_kernel(const float* __restrict__ mem, const float* __restrict__ mnorm,
                              const float* __restrict__ part, const float* __restrict__ pnorm,
                              float* __restrict__ out_mem, float* __restrict__ out_norm) {
  const int MEMN = B * NH * DH * DH;   // 786432
  int i = blockIdx.x * blockDim.x + threadIdx.x;
  if (i < MEMN / 4) {
    int i4 = i * 4;
    float4 a = *(const float4*)(mem + i4);
    #pragma unroll
    for (int c = 0; c < MU_CHUNK; c++) {
      float4 p = *(const float4*)(part + (size_t)c * MEMN + i4);
      a.x += p.x; a.y += p.y; a.z += p.z; a.w += p.w;
    }
    *(float4*)(out_mem + i4) = a;
  } else {
    int j4 = (i - MEMN / 4) * 4;
    if (j4 < B * NH * DH) {
      float4 a = *(const float4*)(mnorm + j4);
      #pragma unroll
      for (int c = 0; c < MU_CHUNK; c++) {
        float4 p = *(const float4*)(pnorm + (size_t)c * (B * NH * DH) + j4);
        a.x += p.x; a.y += p.y; a.z += p.z; a.w += p.w;
      }
      *(float4*)(out_norm + j4) = a;
    }
  }
}

// out = layer_norm(x + y, g, b); one block per row of 768 (fallback path).
template <typename TX, typename TY>
__global__ void addln_kernel(const TX* __restrict__ x, const TY* __restrict__ y,
                             const float* __restrict__ g, const float* __restrict__ bb,
                             float* __restrict__ outf, bf16* __restrict__ outb) {
  int row = blockIdx.x;
  int t = threadIdx.x;      // 256
  float vals[3];
  float sum = 0.0f, sq = 0.0f;
  #pragma unroll
  for (int i = 0; i < 3; i++) {
    size_t idx = (size_t)row * Dm + t + i * 256;
    float vv = ldv(x, idx) + ldv(y, idx);
    vals[i] = vv;
    sum += vv;
    sq += vv * vv;
  }
  sum = wave_sum(sum);
  sq = wave_sum(sq);
  __shared__ float s1[4], s2[4];
  int w = t >> 6, lane = t & 63;
  if (lane == 0) { s1[w] = sum; s2[w] = sq; }
  __syncthreads();
  if (t == 0) {
    s1[0] = s1[0] + s1[1] + s1[2] + s1[3];
    s2[0] = s2[0] + s2[1] + s2[2] + s2[3];
  }
  __syncthreads();
  sum = s1[0]; sq = s2[0];
  float mu = sum / 768.0f;
  float var = sq / 768.0f - mu * mu;
  float rs = rsqrtf(var + 1e-5f);
  #pragma unroll
  for (int i = 0; i < 3; i++) {
    int d = t + i * 256;
    float o = (vals[i] - mu) * rs * g[d] + bb[d];
    size_t idx = (size_t)row * Dm + d;
    if (outf) outf[idx] = o;
    if (outb) outb[idx] = f2b(o);
  }
}

// out = layer_norm(x + sum_z part[z] + bias, g, b) — fused split-K reduce + LN.
template <int NSLICE, typename TX>
__global__ void addln_red_kernel(const TX* __restrict__ x, const float* __restrict__ part,
                                 const float* __restrict__ bias,
                                 const float* __restrict__ g, const float* __restrict__ bb,
                                 float* __restrict__ outf, bf16* __restrict__ outb) {
  const size_t SBDc = (size_t)S * B * Dm;
  int row = blockIdx.x;
  int t = threadIdx.x;      // 256
  float vals[3];
  float sum = 0.0f, sq = 0.0f;
  #pragma unroll
  for (int i = 0; i < 3; i++) {
    int d = t + i * 256;
    size_t idx = (size_t)row * Dm + d;
    float y = part[idx];
    #pragma unroll
    for (int z = 1; z < NSLICE; z++) y += part[(size_t)z * SBDc + idx];
    if (bias) y += bias[d];
    float vv = ldv(x, idx) + y;
    vals[i] = vv;
    sum += vv;
    sq += vv * vv;
  }
  sum = wave_sum(sum);
  sq = wave_sum(sq);
  __shared__ float s1[4], s2[4];
  int w = t >> 6, lane = t & 63;
  if (lane == 0) { s1[w] = sum; s2[w] = sq; }
  __syncthreads();
  if (t == 0) {
    s1[0] = s1[0] + s1[1] + s1[2] + s1[3];
    s2[0] = s2[0] + s2[1] + s2[2] + s2[3];
  }
  __syncthreads();
  sum = s1[0]; sq = s2[0];
  float mu = sum / 768.0f;
  float var = sq / 768.0f - mu * mu;
  float rs = rsqrtf(var + 1e-5f);
  #pragma unroll
  for (int i = 0; i < 3; i++) {
    int d = t + i * 256;
    float o = (vals[i] - mu) * rs * g[d] + bb[d];
    size_t idx = (size_t)row * Dm + d;
    if (outf) outf[idx] = o;
    if (outb) outb[idx] = f2b(o);
  }
}

extern "C" void kernel_launch(void* const* d_in, const int* in_sizes, int n_in,
                              void* d_out, int out_size, void* d_ws, size_t ws_size,
                              hipStream_t stream) {
  (void)in_sizes; (void)n_in; (void)out_size;
  const int*   inp   = (const int*)d_in[0];
  const float* wemb  = (const float*)d_in[1];
  const float* Wq    = (const float*)d_in[2];
  const float* Wkv   = (const float*)d_in[3];
  const float* Wo    = (const float*)d_in[4];
  const float* ln1g  = (const float*)d_in[5];
  const float* ln1b  = (const float*)d_in[6];
  const float* fW1   = (const float*)d_in[7];
  const float* fb1   = (const float*)d_in[8];
  const float* fW2   = (const float*)d_in[9];
  const float* fb2   = (const float*)d_in[10];
  const float* ln2g  = (const float*)d_in[11];
  const float* ln2b  = (const float*)d_in[12];
  const float* mem   = (const float*)d_in[13];
  const float* mnorm = (const float*)d_in[14];

  const size_t SBD = (size_t)S * B * Dm;   // 3,145,728

  bf16* ws   = (bf16*)d_ws;
  bf16* qkv  = ws;              // slots 0-2: fused qkv, [4096][2304]
  bf16* vd   = ws + 3 * SBD;    // slot 3
  bf16* att  = ws + 4 * SBD;    // slot 4 (aliased: h_bf — disjoint in time)
  bf16* hbf  = att;
  bf16* out1 = ws + 5 * SBD;    // slot 5
  bf16* wb   = ws + 6 * SBD;    // bf16 weight pack for current layer
  bf16* ffm  = ws;              // 4*SBD: aliases slots 0-3 (dead by FF1)
  bf16* tmp  = ws;              // fallback Wo-GEMM out
  bf16* ff2o = att;             // fallback FF2 out
  // memupd partials live in out1 slot (dead during memupd).
  float* part  = (float*)out1;
  float* pnorm = (float*)(wb + SEG_END);   // 96 KiB past wb
  // split-K partials (3 x SBD fp32 = 37.7 MB) past pnorm; also attn pml scratch.
  float* partg = pnorm + (size_t)MU_CHUNK * B * NH * DH;
  const size_t need = ((size_t)(6 * SBD + SEG_END)) * 2 +
                      ((size_t)MU_CHUNK * B * NH * DH + 3 * SBD) * 4;
  const bool use_splitk = (ws_size >= need);
  bf16* po0 = vd;
  bf16* po1 = out1;
  float* pml = partg;

  float* h    = (float*)d_out;  // residual stream lives in d_out (fp32)
  float* outm = h + SBD;
  float* outn = outm + (size_t)NL * B * NH * DH * DH;

  dim3 b256(256);
  embed_kernel<<<dim3((S * B * Dm + 255) / 256), b256, 0, stream>>>(inp, wemb, h, hbf);

  for (int l = 0; l < NL; l++) {
    convw_kernel<<<dim3(SEG_END / 4 / 256), b256, 0, stream>>>(
        Wq + (size_t)l * Dm * Dm, Wkv + (size_t)l * 2 * Dm * Dm,
        Wo + (size_t)l * Dm * Dm, fW1 + (size_t)l * DI * Dm,
        fW2 + (size_t)l * Dm * DI, wb);
    const bf16* wqkv = wb;
    const bf16* wo_b = wb + SEG_QKV;
    const bf16* w1_b = wb + SEG_WO;
    const bf16* w2_b = wb + SEG_W1;
    const float* mem_l = mem + (size_t)l * B * NH * DH * DH;
    const float* mn_l  = mnorm + (size_t)l * B * NH * DH;
    float* outm_l = outm + (size_t)l * B * NH * DH * DH;
    float* outn_l = outn + (size_t)l * B * NH * DH;

    // fused QKV: M=4096, N=2304, K=768 -> 576 blocks (swizzled)
    gemm_async<4, 0, 1, bf16><<<dim3(QS / 128, 32), b256, 0, stream>>>(
        hbf, wqkv, nullptr, qkv, QS, Dm);

    if (use_splitk) {
      attn_flash<2><<<dim3(S / 64, B * NH, 2), b256, 0, stream>>>(
          qkv, qkv + 768, qkv + 1536, att, po0, po1, pml);
      attn_comb<<<dim3((unsigned)(SBD / 4 / 256)), b256, 0, stream>>>(po0, po1, pml, att);
    } else {
      attn_flash<1><<<dim3(S / 64, B * NH), b256, 0, stream>>>(
          qkv, qkv + 768, qkv + 1536, att, nullptr, nullptr, nullptr);
    }
    meminfer_mfma<<<dim3(S / 64, B * NH), b256, 0, stream>>>(qkv, mem_l, mn_l, att, vd);
    memupd_kernel<<<dim3(B * NH * MU_CHUNK), b256, 0, stream>>>(qkv, vd, part, pnorm);
    memred_kernel<<<dim3(771), b256, 0, stream>>>(mem_l, mn_l, part, pnorm, outm_l, outn_l);

    // Wo: M=4096, N=768, K=768
    if (use_splitk) {
      // 128x128 tile, split-K=3: grid (6,32,3)=576 blocks; reduce fused into LN
      gemm_async<4, 0, 3, float><<<dim3(Dm / 128, 32, 3), b256, 0, stream>>>(
          att, wo_b, nullptr, partg, Dm, Dm);
      addln_red_kernel<3, float><<<dim3(S * B), b256, 0, stream>>>(
          h, partg, nullptr, ln1g + l * Dm, ln1b + l * Dm, nullptr, out1);
    } else {
      gemm_async<2, 0, 1, bf16><<<dim3(Dm / 128, 64), b256, 0, stream>>>(
          att, wo_b, nullptr, tmp, Dm, Dm);
      addln_kernel<float, bf16><<<dim3(S * B), b256, 0, stream>>>(
          h, tmp, ln1g + l * Dm, ln1b + l * Dm, nullptr, out1);
    }

    // FF1: M=4096, N=3072, K=768 -> 768 blocks (swizzled)
    gemm_async<4, 1, 1, bf16><<<dim3(DI / 128, 32), b256, 0, stream>>>(
        out1, w1_b, fb1 + (size_t)l * DI, ffm, DI, Dm);
    // FF2: M=4096, N=768, K=3072
    if (use_splitk) {
      gemm_async<4, 0, 3, float><<<dim3(Dm / 128, 32, 3), b256, 0, stream>>>(
          ffm, w2_b, nullptr, partg, Dm, DI);
      addln_red_kernel<3, bf16><<<dim3(S * B), b256, 0, stream>>>(
          out1, partg, fb2 + (size_t)l * Dm, ln2g + l * Dm, ln2b + l * Dm, h, hbf);
    } else {
      gemm_async<2, 0, 1, bf16><<<dim3(Dm / 128, 64), b256, 0, stream>>>(
          ffm, w2_b, fb2 + (size_t)l * Dm, ff2o, Dm, DI);
      addln_kernel<bf16, bf16><<<dim3(S * B), b256, 0, stream>>>(
          out1, ff2o, ln2g + l * Dm, ln2b + l * Dm, h, hbf);
    }
  }
}

// Round 8
// 1273.483 us; speedup vs baseline: 1.0507x; 1.0090x over previous
//
#include <hip/hip_runtime.h>
#include <hip/hip_bf16.h>
#include <math.h>

#define S 1024
#define B 4
#define Dm 768
#define NH 12
#define DH 64
#define NL 4
#define DI 3072
#define QS 2304   // row stride of fused qkv activation buffer
#define MU_CHUNK 8   // S-dim split for memupd
#define NROW (S * B * NH)   // 49152 attention rows

typedef __hip_bfloat16 bf16;
typedef short bf16x8 __attribute__((ext_vector_type(8)));
typedef float f32x4 __attribute__((ext_vector_type(4)));

__device__ __forceinline__ float b2f(bf16 x) { return __bfloat162float(x); }
__device__ __forceinline__ bf16 f2b(float x) { return __float2bfloat16(x); }

__device__ __forceinline__ float ldv(const float* p, size_t i) { return p[i]; }
__device__ __forceinline__ float ldv(const bf16* p, size_t i) { return b2f(p[i]); }

__device__ __forceinline__ float wave_sum(float x) {
  #pragma unroll
  for (int off = 32; off > 0; off >>= 1) x += __shfl_xor(x, off, 64);
  return x;
}

// async 16B global -> LDS DMA. LDS dest = wave-uniform base + lane*16.
typedef const __attribute__((address_space(1))) unsigned int guint;
typedef __attribute__((address_space(3))) unsigned int luint;
__device__ __forceinline__ void async_cp16(const void* g, void* l) {
  __builtin_amdgcn_global_load_lds((guint*)g, (luint*)l, 16, 0, 0);
}

// h[s,b,d] = word_emb[inp[s,b], d] * sqrt(D) + pos_emb(s, d); fp32 + bf16 copies
__global__ void embed_kernel(const int* __restrict__ inp, const float* __restrict__ wemb,
                             float* __restrict__ h, bf16* __restrict__ hb) {
  int idx = blockIdx.x * blockDim.x + threadIdx.x;
  if (idx >= S * B * Dm) return;
  int d = idx % Dm;
  int sb = idx / Dm;
  int b = sb % B;
  int s = sb / B;
  int tok = inp[s * B + b];
  float e = wemb[(size_t)tok * Dm + d] * 27.712812921102035f; // sqrt(768)
  float ps = (float)(S - 1 - s);
  float pe;
  if (d < Dm / 2) {
    float invf = expf(-(2.0f * (float)d / (float)Dm) * 9.210340371976184f); // ln(10000)
    pe = sinf(ps * invf);
  } else {
    int j = d - Dm / 2;
    float invf = expf(-(2.0f * (float)j / (float)Dm) * 9.210340371976184f);
    pe = cosf(ps * invf);
  }
  float val = e + pe;
  h[idx] = val;
  hb[idx] = f2b(val);
}

// pack one layer's weights to bf16 into wb:
//   [qkv 2304x768 | wo 768x768 | w1 3072x768 | w2 768x3072]  (all B^T, K contiguous)
#define SEG_QKV 1769472
#define SEG_WO  2359296
#define SEG_W1  4718592
#define SEG_END 7077888
__global__ void convw_kernel(const float* __restrict__ Wq, const float* __restrict__ Wkv,
                             const float* __restrict__ Wo, const float* __restrict__ W1,
                             const float* __restrict__ W2, bf16* __restrict__ dst) {
  int idx = (blockIdx.x * blockDim.x + threadIdx.x) * 4;
  if (idx >= SEG_END) return;
  const float* src;
  if (idx < SEG_QKV) {
    src = (idx < 589824) ? Wq + idx : Wkv + (idx - 589824);
  } else if (idx < SEG_WO) {
    src = Wo + (idx - SEG_QKV);
  } else if (idx < SEG_W1) {
    src = W1 + (idx - SEG_WO);
  } else {
    src = W2 + (idx - SEG_W1);
  }
  float4 f = *(const float4*)src;
  bf16 b0 = f2b(f.x), b1 = f2b(f.y), b2 = f2b(f.z), b3 = f2b(f.w);
  unsigned short o[4];
  o[0] = *(unsigned short*)&b0; o[1] = *(unsigned short*)&b1;
  o[2] = *(unsigned short*)&b2; o[3] = *(unsigned short*)&b3;
  *(uint2*)((unsigned short*)dst + idx) = *(uint2*)o;
}

// C[M,N] = A[M,K] @ W[N,K]^T (+bias)(+relu). bf16 in, fp32 acc, OT out.
// 256 thr = 4 waves (2x2). BN=128, BM=32*MREP, BK=32. Double-buffered 2-phase
// K-loop (stage t+1 before compute t). SPLITK>1: blockIdx.z selects K-chunk,
// fp32 partials at slice stride gridDim.y*BM*ldc (reduced by addln_red).
// XCD-aware bijective swizzle (requires nwg%8==0).
template <int MREP, int RELU, int SPLITK, typename OT>
__global__ __launch_bounds__(256) void gemm_async(const bf16* __restrict__ A,
                                                  const bf16* __restrict__ W,
                                                  const float* __restrict__ bias,
                                                  OT* __restrict__ C,
                                                  int ldc, int K) {
  constexpr int BM = MREP * 32;
  __shared__ __align__(16) unsigned short Asm[2][BM * 32];
  __shared__ __align__(16) unsigned short Bsm[2][128 * 32];
  const int t = threadIdx.x;
  const int w = t >> 6, lane = t & 63;
  const int col = lane & 15, quad = lane >> 4;
  const int wm = w >> 1, wn = w & 1;

  int bx = blockIdx.x, by = blockIdx.y;
  {
    const int nwg = gridDim.x * gridDim.y;
    if ((nwg & 7) == 0) {
      int orig = by * gridDim.x + bx;
      int cpx = nwg >> 3;
      int wg2 = (orig & 7) * cpx + (orig >> 3);
      bx = wg2 % gridDim.x;
      by = wg2 / gridDim.x;
    }
  }
  const int m0 = by * BM, n0 = bx * 128;
  const int Kc = K / SPLITK;
  const int kbeg = (SPLITK > 1) ? blockIdx.z * Kc : 0;

  const bf16* aSrc = A + (size_t)(m0 + w * 16 + col) * K + kbeg + quad * 8;
  const bf16* bSrc = W + (size_t)(n0 + w * 16 + col) * K + kbeg + quad * 8;

  const f32x4 zf = {0.0f, 0.0f, 0.0f, 0.0f};
  f32x4 acc[MREP][4];
  #pragma unroll
  for (int mt = 0; mt < MREP; mt++)
    #pragma unroll
    for (int nt = 0; nt < 4; nt++) acc[mt][nt] = zf;

  // prologue: stage tile 0 into buf 0
  #pragma unroll
  for (int i = 0; i < MREP / 2; i++)
    async_cp16(aSrc + (size_t)i * 64 * K, &Asm[0][i * 2048 + w * 512]);
  #pragma unroll
  for (int i = 0; i < 2; i++)
    async_cp16(bSrc + (size_t)i * 64 * K, &Bsm[0][i * 2048 + w * 512]);
  __syncthreads();                 // vmcnt(0) drain before barrier

  int cur = 0;
  for (int kk = 32; kk < Kc; kk += 32) {
    #pragma unroll
    for (int i = 0; i < MREP / 2; i++)
      async_cp16(aSrc + kk + (size_t)i * 64 * K, &Asm[cur ^ 1][i * 2048 + w * 512]);
    #pragma unroll
    for (int i = 0; i < 2; i++)
      async_cp16(bSrc + kk + (size_t)i * 64 * K, &Bsm[cur ^ 1][i * 2048 + w * 512]);
    bf16x8 af[MREP], bfr[4];
    #pragma unroll
    for (int mt = 0; mt < MREP; mt++)
      af[mt] = *(const bf16x8*)&Asm[cur][(wm * MREP + mt) * 512 + lane * 8];
    #pragma unroll
    for (int nt = 0; nt < 4; nt++)
      bfr[nt] = *(const bf16x8*)&Bsm[cur][(wn * 4 + nt) * 512 + lane * 8];
    #pragma unroll
    for (int mt = 0; mt < MREP; mt++)
      #pragma unroll
      for (int nt = 0; nt < 4; nt++)
        acc[mt][nt] = __builtin_amdgcn_mfma_f32_16x16x32_bf16(af[mt], bfr[nt],
                                                              acc[mt][nt], 0, 0, 0);
    __syncthreads();               // drains next-tile stage; protects buf reuse
    cur ^= 1;
  }
  {
    bf16x8 af[MREP], bfr[4];
    #pragma unroll
    for (int mt = 0; mt < MREP; mt++)
      af[mt] = *(const bf16x8*)&Asm[cur][(wm * MREP + mt) * 512 + lane * 8];
    #pragma unroll
    for (int nt = 0; nt < 4; nt++)
      bfr[nt] = *(const bf16x8*)&Bsm[cur][(wn * 4 + nt) * 512 + lane * 8];
    #pragma unroll
    for (int mt = 0; mt < MREP; mt++)
      #pragma unroll
      for (int nt = 0; nt < 4; nt++)
        acc[mt][nt] = __builtin_amdgcn_mfma_f32_16x16x32_bf16(af[mt], bfr[nt],
                                                              acc[mt][nt], 0, 0, 0);
  }

  OT* Cb = C;
  if (SPLITK > 1)
    Cb = C + (size_t)blockIdx.z * gridDim.y * BM * ldc;
  #pragma unroll
  for (int nt = 0; nt < 4; nt++) {
    const int colg = n0 + wn * 64 + nt * 16 + col;
    const float bv = bias ? bias[colg] : 0.0f;
    #pragma unroll
    for (int mt = 0; mt < MREP; mt++) {
      #pragma unroll
      for (int r = 0; r < 4; r++) {
        const int row = m0 + wm * (MREP * 16) + mt * 16 + quad * 4 + r;
        float val = acc[mt][nt][r] + bv;
        if (RELU) val = fmaxf(val, 0.0f);
        if constexpr (__is_same(OT, float)) {
          Cb[(size_t)row * ldc + colg] = val;
        } else {
          Cb[(size_t)row * ldc + colg] = f2b(val);
        }
      }
    }
  }
}

// one-shot V transpose: vt[bn][d][s] = V[s][b][n*DH+d]  (so attn stages V like K,
// replacing the per-iteration 16-way LDS scatter with coalesced uint4 stores)
__global__ __launch_bounds__(256) void vtrans_kernel(const bf16* __restrict__ v,
                                                     bf16* __restrict__ vt) {
  const int s0 = blockIdx.x * 64;
  const int bn = blockIdx.y;
  const int b = bn / NH, n = bn % NH;
  const int t = threadIdx.x;
  __shared__ __align__(16) unsigned short Tl[64 * 72];
  const unsigned short* vp = (const unsigned short*)v;
  {
    int jj = t >> 2, d0 = (t & 3) * 16;
    size_t gb = ((size_t)(s0 + jj) * B + b) * QS + n * DH + d0;
    unsigned short tv[16];
    *(uint4*)tv = *(const uint4*)(vp + gb);
    *(uint4*)(tv + 8) = *(const uint4*)(vp + gb + 8);
    #pragma unroll
    for (int x = 0; x < 16; x++) Tl[(d0 + x) * 72 + jj] = tv[x];
  }
  __syncthreads();
  {
    int d = t >> 2, so = (t & 3) * 16;
    unsigned short* op = (unsigned short*)vt + ((size_t)bn * 64 + d) * S + s0 + so;
    *(uint4*)op = *(const uint4*)&Tl[d * 72 + so];
    *(uint4*)(op + 8) = *(const uint4*)&Tl[d * 72 + so + 8];
  }
}

// Flash attention with MFMA. Block = 256 thr = 4 waves; one 64-row Q tile per (b,n).
// SPLIT==2: blockIdx.z halves the causal KV range; partials merged by attn_comb.
// VT==1: V read pre-transposed from vt[bn][d][s] (coalesced; no inner-loop scatter).
// K/V tile jt+1 prefetched into regs while computing tile jt.
template <int SPLIT, int VT>
__global__ __launch_bounds__(256) void attn_flash(const bf16* __restrict__ q,
                                                  const bf16* __restrict__ k,
                                                  const bf16* __restrict__ v,
                                                  const bf16* __restrict__ vtg,
                                                  bf16* __restrict__ att,
                                                  bf16* __restrict__ po0,
                                                  bf16* __restrict__ po1,
                                                  float* __restrict__ pml) {
  const int it = blockIdx.x;       // q-tile index (16)
  const int bn = blockIdx.y;       // b*NH+n (48)
  const int b = bn / NH, n = bn % NH;
  const int t = threadIdx.x;
  const int w = t >> 6, lane = t & 63;
  const int col = lane & 15, quad = lane >> 4;
  const int i0 = it * 64;

  int jbeg = 0, jend = it + 1;
  if (SPLIT == 2) {
    const int half = (it + 2) >> 1;
    if (blockIdx.z == 0) jend = half; else jbeg = half;
    if (jbeg >= jend) return;      // it==0, z==1: nothing to do
  }

  __shared__ __align__(16) unsigned short Kt[64 * 72];  // K[j][d], row stride 72
  __shared__ __align__(16) unsigned short Vt[64 * 72];  // V^T[d][j]
  __shared__ __align__(16) unsigned short Pw[64 * 72];  // per-wave P rows

  const unsigned short* qp = (const unsigned short*)q;
  const unsigned short* kp = (const unsigned short*)k;
  const unsigned short* vp = (const unsigned short*)v;
  const unsigned short* vtp = (const unsigned short*)vtg;

  bf16x8 aq[2];
  {
    size_t qb = ((size_t)(i0 + w * 16 + col) * B + b) * QS + n * DH + quad * 8;
    aq[0] = *(const bf16x8*)(qp + qb);
    aq[1] = *(const bf16x8*)(qp + qb + 32);
  }

  const f32x4 zf = {0.0f, 0.0f, 0.0f, 0.0f};
  float mrow[4], lrow[4];
  f32x4 o[4];
  #pragma unroll
  for (int r = 0; r < 4; r++) { mrow[r] = -1e30f; lrow[r] = 0.0f; }
  #pragma unroll
  for (int db = 0; db < 4; db++) o[db] = zf;

  const int jj = t >> 2;           // staging row: VT? d-index : s-index
  const int d0 = (t & 3) << 4;     // staging offset within 64 (x16 shorts)

  // prologue: load first K/V tile into regs
  uint4 rk0, rk1, rv0, rv1;
  {
    size_t gb = ((size_t)(jbeg * 64 + jj) * B + b) * QS + n * DH + d0;
    rk0 = *(const uint4*)(kp + gb); rk1 = *(const uint4*)(kp + gb + 8);
    if constexpr (VT) {
      size_t gv = ((size_t)bn * 64 + jj) * S + jbeg * 64 + d0;
      rv0 = *(const uint4*)(vtp + gv); rv1 = *(const uint4*)(vtp + gv + 8);
    } else {
      rv0 = *(const uint4*)(vp + gb); rv1 = *(const uint4*)(vp + gb + 8);
    }
  }

  for (int jt = jbeg; jt < jend; jt++) {
    const int j0 = jt * 64;
    __syncthreads();               // prior iteration's LDS reads complete
    {
      *(uint4*)&Kt[jj * 72 + d0] = rk0;
      *(uint4*)&Kt[jj * 72 + d0 + 8] = rk1;
      if constexpr (VT) {
        *(uint4*)&Vt[jj * 72 + d0] = rv0;      // row d=jj, j-offset d0
        *(uint4*)&Vt[jj * 72 + d0 + 8] = rv1;
      } else {
        unsigned short tv[16];
        *(uint4*)tv = rv0;
        *(uint4*)(tv + 8) = rv1;
        #pragma unroll
        for (int x = 0; x < 16; x++) Vt[(d0 + x) * 72 + jj] = tv[x];
      }
    }
    __syncthreads();
    if (jt + 1 < jend) {
      size_t gb = ((size_t)((jt + 1) * 64 + jj) * B + b) * QS + n * DH + d0;
      rk0 = *(const uint4*)(kp + gb); rk1 = *(const uint4*)(kp + gb + 8);
      if constexpr (VT) {
        size_t gv = ((size_t)bn * 64 + jj) * S + (jt + 1) * 64 + d0;
        rv0 = *(const uint4*)(vtp + gv); rv1 = *(const uint4*)(vtp + gv + 8);
      } else {
        rv0 = *(const uint4*)(vp + gb); rv1 = *(const uint4*)(vp + gb + 8);
      }
    }

    f32x4 sf[4];
    #pragma unroll
    for (int nb = 0; nb < 4; nb++) sf[nb] = zf;
    #pragma unroll
    for (int ks = 0; ks < 2; ks++) {
      #pragma unroll
      for (int nb = 0; nb < 4; nb++) {
        bf16x8 kb = *(const bf16x8*)&Kt[(nb * 16 + col) * 72 + ks * 32 + quad * 8];
        sf[nb] = __builtin_amdgcn_mfma_f32_16x16x32_bf16(aq[ks], kb, sf[nb], 0, 0, 0);
      }
    }

    const bool diag = (jt == it);
    #pragma unroll
    for (int r = 0; r < 4; r++) {
      const int irow = i0 + w * 16 + quad * 4 + r;
      float sv[4];
      #pragma unroll
      for (int nb = 0; nb < 4; nb++) {
        float s = sf[nb][r] * 0.125f;
        if (diag && (j0 + nb * 16 + col) > irow) s = -1e30f;
        sv[nb] = s;
      }
      float rm = fmaxf(fmaxf(sv[0], sv[1]), fmaxf(sv[2], sv[3]));
      #pragma unroll
      for (int off = 8; off > 0; off >>= 1) rm = fmaxf(rm, __shfl_xor(rm, off, 64));
      const float mn = fmaxf(mrow[r], rm);
      const float alpha = __expf(mrow[r] - mn);
      mrow[r] = mn;
      float ps = 0.0f;
      #pragma unroll
      for (int nb = 0; nb < 4; nb++) {
        float p = __expf(sv[nb] - mn);
        ps += p;
        bf16 hb = f2b(p);
        Pw[(w * 16 + quad * 4 + r) * 72 + nb * 16 + col] = *(unsigned short*)&hb;
      }
      #pragma unroll
      for (int off = 8; off > 0; off >>= 1) ps += __shfl_xor(ps, off, 64);
      lrow[r] = lrow[r] * alpha + ps;
      #pragma unroll
      for (int db = 0; db < 4; db++) o[db][r] *= alpha;
    }

    #pragma unroll
    for (int ks = 0; ks < 2; ks++) {
      bf16x8 pa = *(const bf16x8*)&Pw[(w * 16 + col) * 72 + ks * 32 + quad * 8];
      #pragma unroll
      for (int db = 0; db < 4; db++) {
        bf16x8 vb = *(const bf16x8*)&Vt[(db * 16 + col) * 72 + ks * 32 + quad * 8];
        o[db] = __builtin_amdgcn_mfma_f32_16x16x32_bf16(pa, vb, o[db], 0, 0, 0);
      }
    }
  }

  if (SPLIT == 1) {
    unsigned short* ap = (unsigned short*)att;
    #pragma unroll
    for (int r = 0; r < 4; r++) {
      const int irow = i0 + w * 16 + quad * 4 + r;
      const float inv = 1.0f / lrow[r];
      size_t ob = ((size_t)irow * B + b) * Dm + n * DH + col;
      #pragma unroll
      for (int db = 0; db < 4; db++) {
        bf16 hb = f2b(o[db][r] * inv);
        ap[ob + db * 16] = *(unsigned short*)&hb;
      }
    }
  } else {
    unsigned short* pp = (unsigned short*)(blockIdx.z ? po1 : po0);
    float* pm = pml + (size_t)blockIdx.z * 2 * NROW;
    float* pl = pm + NROW;
    #pragma unroll
    for (int r = 0; r < 4; r++) {
      const int irow = i0 + w * 16 + quad * 4 + r;
      const float inv = 1.0f / lrow[r];
      size_t ob = ((size_t)irow * B + b) * Dm + n * DH + col;
      #pragma unroll
      for (int db = 0; db < 4; db++) {
        bf16 hb = f2b(o[db][r] * inv);
        pp[ob + db * 16] = *(unsigned short*)&hb;
      }
      if (col == 0) {
        int rix = (irow * B + b) * NH + n;
        pm[rix] = mrow[r];
        pl[rix] = lrow[r];
      }
    }
  }
}

// merge the two KV-split partials
__global__ void attn_comb(const bf16* __restrict__ po0, const bf16* __restrict__ po1,
                          const float* __restrict__ pml, bf16* __restrict__ att) {
  size_t i4 = ((size_t)blockIdx.x * blockDim.x + threadIdx.x) * 4;
  if (i4 >= (size_t)S * B * Dm) return;
  int sb = (int)(i4 / Dm);            // srow*B + b
  int dd = (int)(i4 % Dm);
  int srow = sb / B;
  int it = srow >> 6;
  uint2 a0 = *(const uint2*)((const unsigned short*)po0 + i4);
  if (it == 0) {
    *(uint2*)((unsigned short*)att + i4) = a0;
    return;
  }
  uint2 a1 = *(const uint2*)((const unsigned short*)po1 + i4);
  int rix = sb * NH + (dd >> 6);
  float m0 = pml[rix],            l0 = pml[NROW + rix];
  float m1 = pml[2 * NROW + rix], l1 = pml[3 * NROW + rix];
  float M = fmaxf(m0, m1);
  float w0 = l0 * __expf(m0 - M), w1 = l1 * __expf(m1 - M);
  float inv = 1.0f / (w0 + w1);
  const unsigned short* p0 = (const unsigned short*)&a0;
  const unsigned short* p1 = (const unsigned short*)&a1;
  unsigned short o[4];
  #pragma unroll
  for (int j = 0; j < 4; j++) {
    float val = (w0 * b2f(*(const bf16*)&p0[j]) + w1 * b2f(*(const bf16*)&p1[j])) * inv;
    bf16 hb = f2b(val);
    o[j] = *(unsigned short*)&hb;
  }
  *(uint2*)((unsigned short*)att + i4) = *(uint2*)o;
}

// MFMA meminfer: per (b,n), num[s,v] = cQ[s,:]@mem[:,v], den[s] = cQ[s,:]@mnorm
// via a 5th 16-row B-tile holding mnorm.
__global__ __launch_bounds__(256) void meminfer_mfma(const bf16* __restrict__ qkv,
                                                     const float* __restrict__ mem,
                                                     const float* __restrict__ mnorm,
                                                     bf16* __restrict__ att,
                                                     bf16* __restrict__ vd) {
  const int s0 = blockIdx.x * 64;
  const int bn = blockIdx.y;
  const int b = bn / NH, n = bn % NH;
  const int t = threadIdx.x;
  const int w = t >> 6, lane = t & 63;
  const int col = lane & 15, quad = lane >> 4;

  __shared__ __align__(16) unsigned short CQ[4096];
  __shared__ __align__(16) unsigned short CK[4096];
  __shared__ __align__(16) unsigned short Bm[5120];

  const unsigned short* qp = (const unsigned short*)qkv;

  {
    int r = t >> 2;
    int k0 = (t & 3) * 16;
    size_t gb = ((size_t)(s0 + r) * B + b) * QS + n * DH + k0;
    int abase = (r >> 4) * 1024 + (k0 >> 5) * 512 + ((k0 & 31) >> 3) * 128 + (r & 15) * 8;
    unsigned short tq[16], tv[16], oq[16], ov[16];
    *(uint4*)tq = *(const uint4*)(qp + gb);
    *(uint4*)(tq + 8) = *(const uint4*)(qp + gb + 8);
    *(uint4*)tv = *(const uint4*)(qp + gb + 1536);
    *(uint4*)(tv + 8) = *(const uint4*)(qp + gb + 1536 + 8);
    #pragma unroll
    for (int i = 0; i < 16; i++) {
      float fq = b2f(*(const bf16*)&tq[i]);
      float fv = b2f(*(const bf16*)&tv[i]);
      float eq = fq > 0.0f ? fq + 1.0f : __expf(fq);
      float ev = fv > 0.0f ? fv + 1.0f : __expf(fv);
      bf16 bq = f2b(eq), bv2 = f2b(ev);
      oq[i] = *(unsigned short*)&bq;
      ov[i] = *(unsigned short*)&bv2;
    }
    *(bf16x8*)&CQ[abase] = *(bf16x8*)oq;
    *(bf16x8*)&CQ[abase + 128] = *(bf16x8*)(oq + 8);
    *(bf16x8*)&CK[abase] = *(bf16x8*)ov;
    *(bf16x8*)&CK[abase + 128] = *(bf16x8*)(ov + 8);
  }
  {
    int v = t & 63, kb = (t >> 6) * 16;
    const float* mp = mem + (size_t)bn * DH * DH;
    #pragma unroll
    for (int i = 0; i < 16; i++) {
      int k = kb + i;
      bf16 mb = f2b(mp[(size_t)k * DH + v]);
      int addr = (v >> 4) * 1024 + (k >> 5) * 512 + ((k & 31) >> 3) * 128 + (v & 15) * 8 + (k & 7);
      Bm[addr] = *(unsigned short*)&mb;
    }
  }
  {
    int a = t * 4;
    int m = (a >> 3) & 15;
    int kk = (a >> 9) * 32 + ((a >> 7) & 3) * 8 + (a & 7);
    unsigned short vals[4] = {0, 0, 0, 0};
    if (m == 0) {
      const float* np = mnorm + (size_t)bn * DH;
      #pragma unroll
      for (int j = 0; j < 4; j++) {
        bf16 nb = f2b(np[kk + j]);
        vals[j] = *(unsigned short*)&nb;
      }
    }
    *(uint2*)&Bm[4096 + a] = *(uint2*)vals;
  }
  __syncthreads();

  const f32x4 zf = {0.0f, 0.0f, 0.0f, 0.0f};
  f32x4 aq[5], ak[5];
  #pragma unroll
  for (int nb = 0; nb < 5; nb++) { aq[nb] = zf; ak[nb] = zf; }
  #pragma unroll
  for (int ks = 0; ks < 2; ks++) {
    bf16x8 fq = *(const bf16x8*)&CQ[w * 1024 + ks * 512 + lane * 8];
    bf16x8 fk = *(const bf16x8*)&CK[w * 1024 + ks * 512 + lane * 8];
    #pragma unroll
    for (int nb = 0; nb < 5; nb++) {
      bf16x8 bm = *(const bf16x8*)&Bm[nb * 1024 + ks * 512 + lane * 8];
      aq[nb] = __builtin_amdgcn_mfma_f32_16x16x32_bf16(fq, bm, aq[nb], 0, 0, 0);
      ak[nb] = __builtin_amdgcn_mfma_f32_16x16x32_bf16(fk, bm, ak[nb], 0, 0, 0);
    }
  }

  const float gate = 1.0f / (1.0f + expf(-0.01f));
  unsigned short* ap = (unsigned short*)att;
  unsigned short* vp2 = (unsigned short*)vd;
  #pragma unroll
  for (int r = 0; r < 4; r++) {
    const int srow = s0 + w * 16 + quad * 4 + r;
    const float denq = __shfl(aq[4][r], lane & 48, 64);
    const float denk = __shfl(ak[4][r], lane & 48, 64);
    const size_t bd = ((size_t)srow * B + b) * Dm + n * DH + col;
    const size_t bq = ((size_t)srow * B + b) * QS + 768 + n * DH + col;
    #pragma unroll
    for (int nb = 0; nb < 4; nb++) {
      float content = aq[nb][r] / denq;
      float delta = ak[nb][r] / denk;
      float attv = b2f(*(const bf16*)&ap[bd + nb * 16]);
      bf16 ao = f2b(gate * content + (1.0f - gate) * attv);
      ap[bd + nb * 16] = *(unsigned short*)&ao;
      float kvv = b2f(*(const bf16*)&qp[bq + nb * 16]);
      bf16 vo = f2b(kvv - delta);
      vp2[bd + nb * 16] = *(unsigned short*)&vo;
    }
  }
}

// pass 1: part[c][bn][k*64+v] = sum_{s in chunk c} cK[s,k]*vd[s,v]
__global__ void memupd_kernel(const bf16* __restrict__ qkv, const bf16* __restrict__ vd,
                              float* __restrict__ part, float* __restrict__ pnorm) {
  int bn = blockIdx.x % (B * NH);
  int c = blockIdx.x / (B * NH);
  int b = bn / NH, n = bn % NH;
  int t = threadIdx.x;        // 256
  int k = t >> 2;             // 0..63
  int v0 = (t & 3) * 16;      // 0,16,32,48
  __shared__ float ckl[8][DH];
  __shared__ float vdl[8][DH];
  float acc[16];
  #pragma unroll
  for (int j = 0; j < 16; j++) acc[j] = 0.0f;
  float nsum = 0.0f;
  const int sBeg = c * (S / MU_CHUNK), sEnd = sBeg + S / MU_CHUNK;
  for (int s0 = sBeg; s0 < sEnd; s0 += 8) {
    #pragma unroll
    for (int i2 = 0; i2 < 2; i2++) {
      int idx = t + i2 * 256;
      int sp = idx >> 6, dd = idx & 63;
      int gq = ((s0 + sp) * B + b) * QS + 1536 + n * DH + dd;   // v
      int gd = ((s0 + sp) * B + b) * Dm + n * DH + dd;          // vd
      float vv = b2f(qkv[gq]);
      ckl[sp][dd] = vv > 0.0f ? vv + 1.0f : expf(vv);
      vdl[sp][dd] = b2f(vd[gd]);
    }
    __syncthreads();
    #pragma unroll
    for (int sp = 0; sp < 8; sp++) {
      float cc = ckl[sp][k];
      if ((t & 3) == 0) nsum += cc;
      #pragma unroll
      for (int j = 0; j < 16; j++) acc[j] += cc * vdl[sp][v0 + j];
    }
    __syncthreads();
  }
  float* prow = part + (size_t)c * (B * NH * DH * DH) + (size_t)bn * DH * DH;
  #pragma unroll
  for (int j4 = 0; j4 < 4; j4++) {
    float4 o;
    o.x = acc[j4 * 4 + 0]; o.y = acc[j4 * 4 + 1];
    o.z = acc[j4 * 4 + 2]; o.w = acc[j4 * 4 + 3];
    *(float4*)&prow[k * DH + v0 + j4 * 4] = o;
  }
  if ((t & 3) == 0) pnorm[(size_t)c * (B * NH * DH) + bn * DH + k] = nsum;
}

// pass 2: out_mem = mem + sum_c part[c];  out_norm = mnorm + sum_c pnorm[c]
__global__ void memred_kernel(const float* __restrict__ mem, const float* __restrict__ mnorm,
                              const float* __restrict__ part, const float* __restrict__ pnorm,
                              float* __restrict__ out_mem, float* __restrict__ out_norm) {
  const int MEMN = B * NH * DH * DH;   // 786432
  int i = blockIdx.x * blockDim.x + threadIdx.x;
  if (i < MEMN / 4) {
    int i4 = i * 4;
    float4 a = *(const float4*)(mem + i4);
    #pragma unroll
    for (int c = 0; c < MU_CHUNK; c++) {
      float4 p = *(const float4*)(part + (size_t)c * MEMN + i4);
      a.x += p.x; a.y += p.y; a.z += p.z; a.w += p.w;
    }
    *(float4*)(out_mem + i4) = a;
  } else {
    int j4 = (i - MEMN / 4) * 4;
    if (j4 < B * NH * DH) {
      float4 a = *(const float4*)(mnorm + j4);
      #pragma unroll
      for (int c = 0; c < MU_CHUNK; c++) {
        float4 p = *(const float4*)(pnorm + (size_t)c * (B * NH * DH) + j4);
        a.x += p.x; a.y += p.y; a.z += p.z; a.w += p.w;
      }
      *(float4*)(out_norm + j4) = a;
    }
  }
}

// out = layer_norm(x + y, g, b); one block per row of 768 (fallback path).
template <typename TX, typename TY>
__global__ void addln_kernel(const TX* __restrict__ x, const TY* __restrict__ y,
                             const float* __restrict__ g, const float* __restrict__ bb,
                             float* __restrict__ outf, bf16* __restrict__ outb) {
  int row = blockIdx.x;
  int t = threadIdx.x;      // 256
  float vals[3];
  float sum = 0.0f, sq = 0.0f;
  #pragma unroll
  for (int i = 0; i < 3; i++) {
    size_t idx = (size_t)row * Dm + t + i * 256;
    float vv = ldv(x, idx) + ldv(y, idx);
    vals[i] = vv;
    sum += vv;
    sq += vv * vv;
  }
  sum = wave_sum(sum);
  sq = wave_sum(sq);
  __shared__ float s1[4], s2[4];
  int w = t >> 6, lane = t & 63;
  if (lane == 0) { s1[w] = sum; s2[w] = sq; }
  __syncthreads();
  if (t == 0) {
    s1[0] = s1[0] + s1[1] + s1[2] + s1[3];
    s2[0] = s2[0] + s2[1] + s2[2] + s2[3];
  }
  __syncthreads();
  sum = s1[0]; sq = s2[0];
  float mu = sum / 768.0f;
  float var = sq / 768.0f - mu * mu;
  float rs = rsqrtf(var + 1e-5f);
  #pragma unroll
  for (int i = 0; i < 3; i++) {
    int d = t + i * 256;
    float o = (vals[i] - mu) * rs * g[d] + bb[d];
    size_t idx = (size_t)row * Dm + d;
    if (outf) outf[idx] = o;
    if (outb) outb[idx] = f2b(o);
  }
}

// out = layer_norm(x + sum_z part[z] + bias, g, b) — fused split-K reduce + LN.
template <int NSLICE, typename TX>
__global__ void addln_red_kernel(const TX* __restrict__ x, const float* __restrict__ part,
                                 const float* __restrict__ bias,
                                 const float* __restrict__ g, const float* __restrict__ bb,
                                 float* __restrict__ outf, bf16* __restrict__ outb) {
  const size_t SBDc = (size_t)S * B * Dm;
  int row = blockIdx.x;
  int t = threadIdx.x;      // 256
  float vals[3];
  float sum = 0.0f, sq = 0.0f;
  #pragma unroll
  for (int i = 0; i < 3; i++) {
    int d = t + i * 256;
    size_t idx = (size_t)row * Dm + d;
    float y = part[idx];
    #pragma unroll
    for (int z = 1; z < NSLICE; z++) y += part[(size_t)z * SBDc + idx];
    if (bias) y += bias[d];
    float vv = ldv(x, idx) + y;
    vals[i] = vv;
    sum += vv;
    sq += vv * vv;
  }
  sum = wave_sum(sum);
  sq = wave_sum(sq);
  __shared__ float s1[4], s2[4];
  int w = t >> 6, lane = t & 63;
  if (lane == 0) { s1[w] = sum; s2[w] = sq; }
  __syncthreads();
  if (t == 0) {
    s1[0] = s1[0] + s1[1] + s1[2] + s1[3];
    s2[0] = s2[0] + s2[1] + s2[2] + s2[3];
  }
  __syncthreads();
  sum = s1[0]; sq = s2[0];
  float mu = sum / 768.0f;
  float var = sq / 768.0f - mu * mu;
  float rs = rsqrtf(var + 1e-5f);
  #pragma unroll
  for (int i = 0; i < 3; i++) {
    int d = t + i * 256;
    float o = (vals[i] - mu) * rs * g[d] + bb[d];
    size_t idx = (size_t)row * Dm + d;
    if (outf) outf[idx] = o;
    if (outb) outb[idx] = f2b(o);
  }
}

extern "C" void kernel_launch(void* const* d_in, const int* in_sizes, int n_in,
                              void* d_out, int out_size, void* d_ws, size_t ws_size,
                              hipStream_t stream) {
  (void)in_sizes; (void)n_in; (void)out_size;
  const int*   inp   = (const int*)d_in[0];
  const float* wemb  = (const float*)d_in[1];
  const float* Wq    = (const float*)d_in[2];
  const float* Wkv   = (const float*)d_in[3];
  const float* Wo    = (const float*)d_in[4];
  const float* ln1g  = (const float*)d_in[5];
  const float* ln1b  = (const float*)d_in[6];
  const float* fW1   = (const float*)d_in[7];
  const float* fb1   = (const float*)d_in[8];
  const float* fW2   = (const float*)d_in[9];
  const float* fb2   = (const float*)d_in[10];
  const float* ln2g  = (const float*)d_in[11];
  const float* ln2b  = (const float*)d_in[12];
  const float* mem   = (const float*)d_in[13];
  const float* mnorm = (const float*)d_in[14];

  const size_t SBD = (size_t)S * B * Dm;   // 3,145,728

  bf16* ws   = (bf16*)d_ws;
  bf16* qkv  = ws;              // slots 0-2: fused qkv, [4096][2304]
  bf16* vd   = ws + 3 * SBD;    // slot 3
  bf16* att  = ws + 4 * SBD;    // slot 4 (aliased: h_bf — disjoint in time)
  bf16* hbf  = att;
  bf16* out1 = ws + 5 * SBD;    // slot 5
  bf16* wb   = ws + 6 * SBD;    // bf16 weight pack for current layer
  bf16* ffm  = ws;              // 4*SBD: aliases slots 0-3 (dead by FF1)
  bf16* tmp  = ws;              // fallback Wo-GEMM out
  bf16* ff2o = att;             // fallback FF2 out
  // memupd partials live in out1 slot (dead during memupd).
  float* part  = (float*)out1;
  float* pnorm = (float*)(wb + SEG_END);   // 96 KiB past wb
  // split-K partials (3 x SBD fp32 = 37.7 MB) past pnorm; also attn pml + vt scratch.
  float* partg = pnorm + (size_t)MU_CHUNK * B * NH * DH;
  const size_t need = ((size_t)(6 * SBD + SEG_END)) * 2 +
                      ((size_t)MU_CHUNK * B * NH * DH + 3 * SBD) * 4;
  const bool use_splitk = (ws_size >= need);
  bf16* po0 = vd;
  bf16* po1 = out1;
  float* pml = partg;
  bf16* vt  = (bf16*)(partg + 4 * NROW);   // 6.3 MB, dead outside attn phase

  float* h    = (float*)d_out;  // residual stream lives in d_out (fp32)
  float* outm = h + SBD;
  float* outn = outm + (size_t)NL * B * NH * DH * DH;

  dim3 b256(256);
  embed_kernel<<<dim3((S * B * Dm + 255) / 256), b256, 0, stream>>>(inp, wemb, h, hbf);

  for (int l = 0; l < NL; l++) {
    convw_kernel<<<dim3(SEG_END / 4 / 256), b256, 0, stream>>>(
        Wq + (size_t)l * Dm * Dm, Wkv + (size_t)l * 2 * Dm * Dm,
        Wo + (size_t)l * Dm * Dm, fW1 + (size_t)l * DI * Dm,
        fW2 + (size_t)l * Dm * DI, wb);
    const bf16* wqkv = wb;
    const bf16* wo_b = wb + SEG_QKV;
    const bf16* w1_b = wb + SEG_WO;
    const bf16* w2_b = wb + SEG_W1;
    const float* mem_l = mem + (size_t)l * B * NH * DH * DH;
    const float* mn_l  = mnorm + (size_t)l * B * NH * DH;
    float* outm_l = outm + (size_t)l * B * NH * DH * DH;
    float* outn_l = outn + (size_t)l * B * NH * DH;

    // fused QKV: M=4096, N=2304, K=768 -> 576 blocks (swizzled)
    gemm_async<4, 0, 1, bf16><<<dim3(QS / 128, 32), b256, 0, stream>>>(
        hbf, wqkv, nullptr, qkv, QS, Dm);

    if (use_splitk) {
      vtrans_kernel<<<dim3(S / 64, B * NH), b256, 0, stream>>>(qkv + 1536, vt);
      attn_flash<2, 1><<<dim3(S / 64, B * NH, 2), b256, 0, stream>>>(
          qkv, qkv + 768, qkv + 1536, vt, att, po0, po1, pml);
      attn_comb<<<dim3((unsigned)(SBD / 4 / 256)), b256, 0, stream>>>(po0, po1, pml, att);
    } else {
      attn_flash<1, 0><<<dim3(S / 64, B * NH), b256, 0, stream>>>(
          qkv, qkv + 768, qkv + 1536, nullptr, att, nullptr, nullptr, nullptr);
    }
    meminfer_mfma<<<dim3(S / 64, B * NH), b256, 0, stream>>>(qkv, mem_l, mn_l, att, vd);
    memupd_kernel<<<dim3(B * NH * MU_CHUNK), b256, 0, stream>>>(qkv, vd, part, pnorm);
    memred_kernel<<<dim3(771), b256, 0, stream>>>(mem_l, mn_l, part, pnorm, outm_l, outn_l);

    // Wo: M=4096, N=768, K=768
    if (use_splitk) {
      gemm_async<4, 0, 3, float><<<dim3(Dm / 128, 32, 3), b256, 0, stream>>>(
          att, wo_b, nullptr, partg, Dm, Dm);
      addln_red_kernel<3, float><<<dim3(S * B), b256, 0, stream>>>(
          h, partg, nullptr, ln1g + l * Dm, ln1b + l * Dm, nullptr, out1);
    } else {
      gemm_async<2, 0, 1, bf16><<<dim3(Dm / 128, 64), b256, 0, stream>>>(
          att, wo_b, nullptr, tmp, Dm, Dm);
      addln_kernel<float, bf16><<<dim3(S * B), b256, 0, stream>>>(
          h, tmp, ln1g + l * Dm, ln1b + l * Dm, nullptr, out1);
    }

    // FF1: M=4096, N=3072, K=768 -> 768 blocks (swizzled)
    gemm_async<4, 1, 1, bf16><<<dim3(DI / 128, 32), b256, 0, stream>>>(
        out1, w1_b, fb1 + (size_t)l * DI, ffm, DI, Dm);
    // FF2: M=4096, N=768, K=3072
    if (use_splitk) {
      gemm_async<4, 0, 3, float><<<dim3(Dm / 128, 32, 3), b256, 0, stream>>>(
          ffm, w2_b, nullptr, partg, Dm, DI);
      addln_red_kernel<3, bf16><<<dim3(S * B), b256, 0, stream>>>(
          out1, partg, fb2 + (size_t)l * Dm, ln2g + l * Dm, ln2b + l * Dm, h, hbf);
    } else {
      gemm_async<2, 0, 1, bf16><<<dim3(Dm / 128, 64), b256, 0, stream>>>(
          ffm, w2_b, fb2 + (size_t)l * Dm, ff2o, Dm, DI);
      addln_kernel<bf16, bf16><<<dim3(S * B), b256, 0, stream>>>(
          out1, ff2o, ln2g + l * Dm, ln2b + l * Dm, h, hbf);
    }
  }
}